// Round 1
// baseline (418.863 us; speedup 1.0000x reference)
//
#include <hip/hip_runtime.h>
#include <math.h>

#define HEADS 4
#define HDIM 32
#define FDIM 128   // HEADS*HDIM
#define NGRAPH 128
#define NCLASS 10
#define NPW 8      // nodes per wave in layer-2 GEMM

__device__ __forceinline__ float lrelu(float x) { return fmaxf(x, 0.2f * x); }

// ---------------- histogram of dst (in-degree) ----------------
__global__ void k_hist(const int* __restrict__ dst, int* __restrict__ deg, int E) {
    int i = blockIdx.x * blockDim.x + threadIdx.x;
    if (i < E) atomicAdd(&deg[dst[i]], 1);
}

// ---------------- exclusive scan, single block of 1024 ----------------
__global__ void k_scan(const int* __restrict__ deg, int* __restrict__ offs, int n) {
    __shared__ int wsum[16];
    __shared__ int s_carry;
    int tid = threadIdx.x, lane = tid & 63, w = tid >> 6;
    if (tid == 0) s_carry = 0;
    __syncthreads();
    for (int base = 0; base < n; base += 1024) {
        int i = base + tid;
        int x = (i < n) ? deg[i] : 0;
        int v = x;
        #pragma unroll
        for (int off = 1; off < 64; off <<= 1) {
            int y = __shfl_up(v, off);
            if (lane >= off) v += y;
        }
        if (lane == 63) wsum[w] = v;
        __syncthreads();
        if (tid == 0) {
            int acc = s_carry;
            #pragma unroll
            for (int j = 0; j < 16; ++j) { int t = wsum[j]; wsum[j] = acc; acc += t; }
            s_carry = acc;
        }
        __syncthreads();
        if (i < n) offs[i] = wsum[w] + (v - x);   // exclusive
        __syncthreads();
    }
    if (threadIdx.x == 0) offs[n] = s_carry;
}

// ---------------- CSR scatter (store src per slot) ----------------
__global__ void k_scatter(const int* __restrict__ src, const int* __restrict__ dst,
                          const int* __restrict__ offs, int* __restrict__ cursor,
                          int* __restrict__ csr_src, int E) {
    int i = blockIdx.x * blockDim.x + threadIdx.x;
    if (i < E) {
        int d = dst[i];
        int p = atomicAdd(&cursor[d], 1);
        csr_src[offs[d] + p] = src[i];
    }
}

// ---------------- layer 1: h0(deg) @ W1 + attention coeffs ----------------
__global__ void k_layer1(const int* __restrict__ deg, const float* __restrict__ W1,
                         const float* __restrict__ al, const float* __restrict__ ar,
                         float* __restrict__ ft, float* __restrict__ a1,
                         float* __restrict__ a2, int n) {
    int wv = (blockIdx.x * blockDim.x + threadIdx.x) >> 6;
    int lane = threadIdx.x & 63;
    if (wv >= n) return;
    int v = wv;
    float d  = (float)deg[v];
    float h0 = d;
    float h1 = (d - 3.0f > 0.0f) ? 1.0f : 0.0f;
    float h2 = 3.0f / d;
    float h3 = (d - 4.0f > 0.0f) ? 1.0f : 0.0f;
    int f = 2 * lane;
    float2 w0 = *(const float2*)(W1 + 0 * FDIM + f);
    float2 w1 = *(const float2*)(W1 + 1 * FDIM + f);
    float2 w2 = *(const float2*)(W1 + 2 * FDIM + f);
    float2 w3 = *(const float2*)(W1 + 3 * FDIM + f);
    float2 acc;
    acc.x = h0 * w0.x + h1 * w1.x + h2 * w2.x + h3 * w3.x;
    acc.y = h0 * w0.y + h1 * w1.y + h2 * w2.y + h3 * w3.y;
    *(float2*)(ft + (size_t)v * FDIM + f) = acc;
    float2 alv = *(const float2*)(al + f);
    float2 arv = *(const float2*)(ar + f);
    float s1 = acc.x * alv.x + acc.y * alv.y;
    float s2 = acc.x * arv.x + acc.y * arv.y;
    #pragma unroll
    for (int off = 1; off < 16; off <<= 1) {
        s1 += __shfl_xor(s1, off);
        s2 += __shfl_xor(s2, off);
    }
    if ((lane & 15) == 0) {
        int h = lane >> 4;
        a1[v * HEADS + h] = s1;
        a2[v * HEADS + h] = s2;
    }
}

// ---------------- wave-per-node segment softmax + aggregate ----------------
__global__ void k_aggregate(const int* __restrict__ offs, const int* __restrict__ csr_src,
                            const float* __restrict__ ft, const float* __restrict__ a1,
                            const float* __restrict__ a2, float* __restrict__ out, int n) {
    int wv = (blockIdx.x * blockDim.x + threadIdx.x) >> 6;
    int lane = threadIdx.x & 63;
    if (wv >= n) return;
    int v = wv;
    int beg = offs[v], end = offs[v + 1];
    float4 a2v = *(const float4*)(a2 + v * HEADS);
    // pass 1: per-head max over incoming edges (lane-strided)
    float m0 = -INFINITY, m1 = -INFINITY, m2 = -INFINITY, m3 = -INFINITY;
    for (int i = beg + lane; i < end; i += 64) {
        int u = csr_src[i];
        float4 a1u = *(const float4*)(a1 + u * HEADS);
        m0 = fmaxf(m0, lrelu(a1u.x + a2v.x));
        m1 = fmaxf(m1, lrelu(a1u.y + a2v.y));
        m2 = fmaxf(m2, lrelu(a1u.z + a2v.z));
        m3 = fmaxf(m3, lrelu(a1u.w + a2v.w));
    }
    #pragma unroll
    for (int off = 1; off < 64; off <<= 1) {
        m0 = fmaxf(m0, __shfl_xor(m0, off));
        m1 = fmaxf(m1, __shfl_xor(m1, off));
        m2 = fmaxf(m2, __shfl_xor(m2, off));
        m3 = fmaxf(m3, __shfl_xor(m3, off));
    }
    // pass 2: per-head sum of exp (lane-strided)
    float s0 = 0.f, s1 = 0.f, s2 = 0.f, s3 = 0.f;
    for (int i = beg + lane; i < end; i += 64) {
        int u = csr_src[i];
        float4 a1u = *(const float4*)(a1 + u * HEADS);
        s0 += __expf(lrelu(a1u.x + a2v.x) - m0);
        s1 += __expf(lrelu(a1u.y + a2v.y) - m1);
        s2 += __expf(lrelu(a1u.z + a2v.z) - m2);
        s3 += __expf(lrelu(a1u.w + a2v.w) - m3);
    }
    #pragma unroll
    for (int off = 1; off < 64; off <<= 1) {
        s0 += __shfl_xor(s0, off);
        s1 += __shfl_xor(s1, off);
        s2 += __shfl_xor(s2, off);
        s3 += __shfl_xor(s3, off);
    }
    // per-lane head params: lane owns features (2l, 2l+1) -> head = lane>>4
    int h = lane >> 4;
    float a2h = (h < 2) ? (h == 0 ? a2v.x : a2v.y) : (h == 2 ? a2v.z : a2v.w);
    float mh  = (h < 2) ? (h == 0 ? m0 : m1) : (h == 2 ? m2 : m3);
    float dh  = (h < 2) ? (h == 0 ? s0 : s1) : (h == 2 ? s2 : s3);
    float rdh = 1.0f / dh;
    float2 acc = make_float2(0.f, 0.f);
    int f = 2 * lane;
    // pass 3: all lanes walk edges together; one coalesced b64 per lane per edge
    for (int i = beg; i < end; ++i) {
        int u = csr_src[i];
        float a1h = a1[u * HEADS + h];
        float alpha = __expf(lrelu(a1h + a2h) - mh) * rdh;
        float2 fv = *(const float2*)(ft + (size_t)u * FDIM + f);
        acc.x += alpha * fv.x;
        acc.y += alpha * fv.y;
    }
    float2 o;
    o.x = fmaxf(acc.x, 0.f);
    o.y = fmaxf(acc.y, 0.f);
    *(float2*)(out + (size_t)v * FDIM + f) = o;
}

// ---------------- layer 2: h @ W2 (W2 staged in LDS) + attention coeffs ----------------
__global__ __launch_bounds__(256) void k_layer2(const float* __restrict__ hin,
        const float* __restrict__ W2, const float* __restrict__ al,
        const float* __restrict__ ar, float* __restrict__ ft,
        float* __restrict__ a1, float* __restrict__ a2, int n) {
    __shared__ float wlds[64 * FDIM];   // 32 KB K-chunk of W2
    int tid = threadIdx.x, lane = tid & 63, w = tid >> 6;
    int wave = blockIdx.x * 4 + w;
    int v0 = wave * NPW;
    int f = 2 * lane;
    float2 acc[NPW];
    #pragma unroll
    for (int j = 0; j < NPW; ++j) acc[j] = make_float2(0.f, 0.f);
    for (int kc = 0; kc < FDIM; kc += 64) {
        __syncthreads();
        #pragma unroll
        for (int t = 0; t < (64 * FDIM / 4) / 256; ++t) {
            int idx = t * 256 + tid;
            ((float4*)wlds)[idx] = ((const float4*)(W2 + kc * FDIM))[idx];
        }
        __syncthreads();
        float hreg[NPW];
        #pragma unroll
        for (int j = 0; j < NPW; ++j) {
            int v = v0 + j; if (v >= n) v = n - 1;
            hreg[j] = hin[(size_t)v * FDIM + kc + lane];   // coalesced
        }
        #pragma unroll 8
        for (int k = 0; k < 64; ++k) {
            float2 wv = *(const float2*)(wlds + k * FDIM + f);
            #pragma unroll
            for (int j = 0; j < NPW; ++j) {
                float hk = __int_as_float(__builtin_amdgcn_readlane(__float_as_int(hreg[j]), k));
                acc[j].x += hk * wv.x;
                acc[j].y += hk * wv.y;
            }
        }
    }
    float2 alv = *(const float2*)(al + f);
    float2 arv = *(const float2*)(ar + f);
    int h = lane >> 4;
    #pragma unroll
    for (int j = 0; j < NPW; ++j) {
        int v = v0 + j;
        if (v < n) *(float2*)(ft + (size_t)v * FDIM + f) = acc[j];
        float s1 = acc[j].x * alv.x + acc[j].y * alv.y;
        float s2 = acc[j].x * arv.x + acc[j].y * arv.y;
        #pragma unroll
        for (int off = 1; off < 16; off <<= 1) {
            s1 += __shfl_xor(s1, off);
            s2 += __shfl_xor(s2, off);
        }
        if (v < n && (lane & 15) == 0) {
            a1[v * HEADS + h] = s1;
            a2[v * HEADS + h] = s2;
        }
    }
}

// ---------------- per-graph mean pooling (run-length + atomics) ----------------
__global__ void k_pool(const float* __restrict__ h, const int* __restrict__ gid,
                       float* __restrict__ gsum, int* __restrict__ gcnt, int n) {
    const int STRIP = 32;
    int wv = (blockIdx.x * blockDim.x + threadIdx.x) >> 6;
    int lane = threadIdx.x & 63;
    int beg = wv * STRIP;
    if (beg >= n) return;
    int end = min(beg + STRIP, n);
    int f = 2 * lane;
    float2 acc = make_float2(0.f, 0.f);
    int cur = gid[beg];
    int cnt = 0;
    for (int i = beg; i < end; ++i) {
        int g = gid[i];
        if (g != cur) {
            atomicAdd(&gsum[cur * FDIM + f], acc.x);
            atomicAdd(&gsum[cur * FDIM + f + 1], acc.y);
            if (lane == 0) atomicAdd(&gcnt[cur], cnt);
            acc = make_float2(0.f, 0.f); cnt = 0; cur = g;
        }
        float2 x = *(const float2*)(h + (size_t)i * FDIM + f);
        acc.x += x.x; acc.y += x.y; cnt++;
    }
    atomicAdd(&gsum[cur * FDIM + f], acc.x);
    atomicAdd(&gsum[cur * FDIM + f + 1], acc.y);
    if (lane == 0) atomicAdd(&gcnt[cur], cnt);
}

// ---------------- classifier ----------------
__global__ void k_classify(const float* __restrict__ gsum, const int* __restrict__ gcnt,
                           const float* __restrict__ Wc, const float* __restrict__ bc,
                           float* __restrict__ out) {
    int idx = blockIdx.x * blockDim.x + threadIdx.x;
    if (idx >= NGRAPH * NCLASS) return;
    int g = idx / NCLASS, c = idx % NCLASS;
    float rc = 1.0f / fmaxf((float)gcnt[g], 1.0f);
    float s = bc[c];
    for (int k = 0; k < FDIM; ++k)
        s += gsum[g * FDIM + k] * rc * Wc[k * NCLASS + c];
    out[idx] = 1.0f / (1.0f + __expf(-s));
}

extern "C" void kernel_launch(void* const* d_in, const int* in_sizes, int n_in,
                              void* d_out, int out_size, void* d_ws, size_t ws_size,
                              hipStream_t stream) {
    const int*   src = (const int*)d_in[0];
    const int*   dst = (const int*)d_in[1];
    const int*   gid = (const int*)d_in[2];
    const float* W1  = (const float*)d_in[3];
    const float* al1 = (const float*)d_in[4];
    const float* ar1 = (const float*)d_in[5];
    const float* W2  = (const float*)d_in[6];
    const float* al2 = (const float*)d_in[7];
    const float* ar2 = (const float*)d_in[8];
    const float* Wc  = (const float*)d_in[9];
    const float* bc  = (const float*)d_in[10];
    float* out = (float*)d_out;
    const int E = in_sizes[0];
    const int N = in_sizes[2];

    char* ws = (char*)d_ws;
    size_t off = 0;
    auto alloc = [&](size_t bytes) -> void* {
        void* p = ws + off;
        off = (off + bytes + 255) & ~(size_t)255;
        return p;
    };
    int*   deg    = (int*)alloc((size_t)N * 4);
    int*   offs   = (int*)alloc((size_t)(N + 1) * 4);
    int*   cursor = (int*)alloc((size_t)N * 4);
    int*   csr    = (int*)alloc((size_t)E * 4);
    float* a1     = (float*)alloc((size_t)N * HEADS * 4);
    float* a2     = (float*)alloc((size_t)N * HEADS * 4);
    float* bufA   = (float*)alloc((size_t)N * FDIM * 4);
    float* bufB   = (float*)alloc((size_t)N * FDIM * 4);
    float* gsum   = (float*)alloc((size_t)NGRAPH * FDIM * 4);
    int*   gcnt   = (int*)alloc((size_t)NGRAPH * 4);

    hipMemsetAsync(deg, 0, (size_t)N * 4, stream);
    hipMemsetAsync(cursor, 0, (size_t)N * 4, stream);
    hipMemsetAsync(gsum, 0, (size_t)NGRAPH * FDIM * 4, stream);
    hipMemsetAsync(gcnt, 0, (size_t)NGRAPH * 4, stream);

    int eb = (E + 255) / 256;
    k_hist<<<eb, 256, 0, stream>>>(dst, deg, E);
    k_scan<<<1, 1024, 0, stream>>>(deg, offs, N);
    k_scatter<<<eb, 256, 0, stream>>>(src, dst, offs, cursor, csr, E);

    int nwb = (N + 3) / 4;   // wave-per-node kernels: 4 waves / 256-thread block
    k_layer1<<<nwb, 256, 0, stream>>>(deg, W1, al1, ar1, bufA, a1, a2, N);
    k_aggregate<<<nwb, 256, 0, stream>>>(offs, csr, bufA, a1, a2, bufB, N);
    int l2b = (N + NPW * 4 - 1) / (NPW * 4);
    k_layer2<<<l2b, 256, 0, stream>>>(bufB, W2, al2, ar2, bufA, a1, a2, N);
    k_aggregate<<<nwb, 256, 0, stream>>>(offs, csr, bufA, a1, a2, bufB, N);

    int pb = (((N + 31) / 32) + 3) / 4;
    k_pool<<<pb, 256, 0, stream>>>(bufB, gid, gsum, gcnt, N);
    k_classify<<<(NGRAPH * NCLASS + 255) / 256, 256, 0, stream>>>(gsum, gcnt, Wc, bc, out);
}

// Round 2
// 307.970 us; speedup vs baseline: 1.3601x; 1.3601x over previous
//
#include <hip/hip_runtime.h>
#include <hip/hip_fp16.h>
#include <math.h>

#define HEADS 4
#define HDIM 32
#define FDIM 128   // HEADS*HDIM
#define NGRAPH 128
#define NCLASS 10
#define NPW 8      // nodes per wave in layer-2 GEMM

__device__ __forceinline__ float lrelu(float x) { return fmaxf(x, 0.2f * x); }
__device__ __forceinline__ float rdlanef(float x, int i) {
    return __int_as_float(__builtin_amdgcn_readlane(__float_as_int(x), i));
}

// ---------------- histogram of dst (in-degree) ----------------
__global__ void k_hist(const int* __restrict__ dst, int* __restrict__ deg, int E) {
    int i = blockIdx.x * blockDim.x + threadIdx.x;
    if (i < E) atomicAdd(&deg[dst[i]], 1);
}

// ---------------- scan step 1: per-block (1024 elems) sums ----------------
__global__ void k_bsum(const int* __restrict__ deg, int* __restrict__ bsum, int n) {
    int tid = threadIdx.x, lane = tid & 63, w = tid >> 6;
    int base = blockIdx.x * 1024 + tid * 4;
    int t = 0;
    #pragma unroll
    for (int k = 0; k < 4; ++k) {
        int i = base + k;
        if (i < n) t += deg[i];
    }
    #pragma unroll
    for (int off = 1; off < 64; off <<= 1) t += __shfl_xor(t, off);
    __shared__ int ws[4];
    if (lane == 0) ws[w] = t;
    __syncthreads();
    if (tid == 0) bsum[blockIdx.x] = ws[0] + ws[1] + ws[2] + ws[3];
}

// ---------------- scan step 2: exclusive scan of block sums (1 wave) ----------------
__global__ void k_bscan(int* __restrict__ bsum, int nb, int* __restrict__ offs,
                        int n, int E) {
    int lane = threadIdx.x;
    int carry = 0;
    for (int base = 0; base < nb; base += 64) {
        int i = base + lane;
        int v = (i < nb) ? bsum[i] : 0;
        int p = v;
        #pragma unroll
        for (int off = 1; off < 64; off <<= 1) {
            int y = __shfl_up(p, off);
            if (lane >= off) p += y;
        }
        if (i < nb) bsum[i] = carry + p - v;   // exclusive
        carry += __shfl(p, 63);
    }
    if (lane == 0) offs[n] = E;
}

// ---------------- scan step 3: per-block exclusive offsets ----------------
__global__ void k_offs(const int* __restrict__ deg, const int* __restrict__ boff,
                       int* __restrict__ offs, int n) {
    int tid = threadIdx.x, lane = tid & 63, w = tid >> 6;
    int base = blockIdx.x * 1024 + tid * 4;
    int v[4]; int t = 0;
    #pragma unroll
    for (int k = 0; k < 4; ++k) {
        int i = base + k;
        v[k] = (i < n) ? deg[i] : 0;
        t += v[k];
    }
    int incl = t;
    #pragma unroll
    for (int off = 1; off < 64; off <<= 1) {
        int y = __shfl_up(incl, off);
        if (lane >= off) incl += y;
    }
    int lpre = incl - t;
    __shared__ int ws[4];
    if (lane == 63) ws[w] = incl;
    __syncthreads();
    int wpre = 0;
    #pragma unroll
    for (int j = 0; j < 4; ++j) if (j < w) wpre += ws[j];
    int g = boff[blockIdx.x] + wpre + lpre;
    #pragma unroll
    for (int k = 0; k < 4; ++k) {
        int i = base + k;
        if (i < n) offs[i] = g;
        g += v[k];
    }
}

// ---------------- CSR scatter (store src per slot) ----------------
__global__ void k_scatter(const int* __restrict__ src, const int* __restrict__ dst,
                          const int* __restrict__ offs, int* __restrict__ cursor,
                          int* __restrict__ csr_src, int E) {
    int i = blockIdx.x * blockDim.x + threadIdx.x;
    if (i < E) {
        int d = dst[i];
        int p = atomicAdd(&cursor[d], 1);
        csr_src[offs[d] + p] = src[i];
    }
}

// ---------------- layer 1: h0(deg) @ W1 + attention coeffs (ft -> fp16) ----------------
__global__ void k_layer1(const int* __restrict__ deg, const float* __restrict__ W1,
                         const float* __restrict__ al, const float* __restrict__ ar,
                         __half* __restrict__ ft, float* __restrict__ a1,
                         float* __restrict__ a2, int n) {
    int wv = (blockIdx.x * blockDim.x + threadIdx.x) >> 6;
    int lane = threadIdx.x & 63;
    if (wv >= n) return;
    int v = wv;
    float d  = (float)deg[v];
    float h0 = d;
    float h1 = (d - 3.0f > 0.0f) ? 1.0f : 0.0f;
    float h2 = 3.0f / d;
    float h3 = (d - 4.0f > 0.0f) ? 1.0f : 0.0f;
    int f = 2 * lane;
    float2 w0 = *(const float2*)(W1 + 0 * FDIM + f);
    float2 w1 = *(const float2*)(W1 + 1 * FDIM + f);
    float2 w2 = *(const float2*)(W1 + 2 * FDIM + f);
    float2 w3 = *(const float2*)(W1 + 3 * FDIM + f);
    float2 acc;
    acc.x = h0 * w0.x + h1 * w1.x + h2 * w2.x + h3 * w3.x;
    acc.y = h0 * w0.y + h1 * w1.y + h2 * w2.y + h3 * w3.y;
    *(__half2*)(ft + (size_t)v * FDIM + f) = __floats2half2_rn(acc.x, acc.y);
    float2 alv = *(const float2*)(al + f);
    float2 arv = *(const float2*)(ar + f);
    float s1 = acc.x * alv.x + acc.y * alv.y;
    float s2 = acc.x * arv.x + acc.y * arv.y;
    #pragma unroll
    for (int off = 1; off < 16; off <<= 1) {
        s1 += __shfl_xor(s1, off);
        s2 += __shfl_xor(s2, off);
    }
    if ((lane & 15) == 0) {
        int h = lane >> 4;
        a1[v * HEADS + h] = s1;
        a2[v * HEADS + h] = s2;
    }
}

// ---------------- wave-per-node segment softmax + aggregate ----------------
__global__ void k_aggregate(const int* __restrict__ offs, const int* __restrict__ csr_src,
                            const __half* __restrict__ ft, const float* __restrict__ a1,
                            const float* __restrict__ a2, float* __restrict__ out, int n) {
    int wv = (blockIdx.x * blockDim.x + threadIdx.x) >> 6;
    int lane = threadIdx.x & 63;
    if (wv >= n) return;
    int v = wv;
    int beg = offs[v], end = offs[v + 1];
    int deg = end - beg;
    float4 a2v = *(const float4*)(a2 + v * HEADS);
    int h = lane >> 4;
    int f = 2 * lane;
    float2 acc = make_float2(0.f, 0.f);

    if (deg <= 64) {
        // -------- fast path: whole softmax in registers --------
        int u = 0;
        float4 e = make_float4(-INFINITY, -INFINITY, -INFINITY, -INFINITY);
        bool act = lane < deg;
        if (act) {
            u = csr_src[beg + lane];
            float4 a1u = *(const float4*)(a1 + u * HEADS);
            e.x = lrelu(a1u.x + a2v.x);
            e.y = lrelu(a1u.y + a2v.y);
            e.z = lrelu(a1u.z + a2v.z);
            e.w = lrelu(a1u.w + a2v.w);
        }
        float4 m = e;
        #pragma unroll
        for (int off = 1; off < 64; off <<= 1) {
            m.x = fmaxf(m.x, __shfl_xor(m.x, off));
            m.y = fmaxf(m.y, __shfl_xor(m.y, off));
            m.z = fmaxf(m.z, __shfl_xor(m.z, off));
            m.w = fmaxf(m.w, __shfl_xor(m.w, off));
        }
        float4 wgt = make_float4(0.f, 0.f, 0.f, 0.f);
        if (act) {
            wgt.x = __expf(e.x - m.x);
            wgt.y = __expf(e.y - m.y);
            wgt.z = __expf(e.z - m.z);
            wgt.w = __expf(e.w - m.w);
        }
        float4 s = wgt;
        #pragma unroll
        for (int off = 1; off < 64; off <<= 1) {
            s.x += __shfl_xor(s.x, off);
            s.y += __shfl_xor(s.y, off);
            s.z += __shfl_xor(s.z, off);
            s.w += __shfl_xor(s.w, off);
        }
        float dh  = (h < 2) ? (h == 0 ? s.x : s.y) : (h == 2 ? s.z : s.w);
        float rdh = 1.0f / dh;
        for (int i = 0; i < deg; ++i) {
            int ui   = __builtin_amdgcn_readlane(u, i);
            float w0 = rdlanef(wgt.x, i), w1 = rdlanef(wgt.y, i);
            float w2 = rdlanef(wgt.z, i), w3 = rdlanef(wgt.w, i);
            float wh = (h < 2) ? (h == 0 ? w0 : w1) : (h == 2 ? w2 : w3);
            float alpha = wh * rdh;
            __half2 hv = *(const __half2*)(ft + (size_t)ui * FDIM + f);
            float2 fv = __half22float2(hv);
            acc.x = fmaf(alpha, fv.x, acc.x);
            acc.y = fmaf(alpha, fv.y, acc.y);
        }
    } else {
        // -------- slow path (deg > 64): 3-pass recompute --------
        float m0 = -INFINITY, m1 = -INFINITY, m2 = -INFINITY, m3 = -INFINITY;
        for (int i = beg + lane; i < end; i += 64) {
            int u = csr_src[i];
            float4 a1u = *(const float4*)(a1 + u * HEADS);
            m0 = fmaxf(m0, lrelu(a1u.x + a2v.x));
            m1 = fmaxf(m1, lrelu(a1u.y + a2v.y));
            m2 = fmaxf(m2, lrelu(a1u.z + a2v.z));
            m3 = fmaxf(m3, lrelu(a1u.w + a2v.w));
        }
        #pragma unroll
        for (int off = 1; off < 64; off <<= 1) {
            m0 = fmaxf(m0, __shfl_xor(m0, off));
            m1 = fmaxf(m1, __shfl_xor(m1, off));
            m2 = fmaxf(m2, __shfl_xor(m2, off));
            m3 = fmaxf(m3, __shfl_xor(m3, off));
        }
        float s0 = 0.f, s1 = 0.f, s2 = 0.f, s3 = 0.f;
        for (int i = beg + lane; i < end; i += 64) {
            int u = csr_src[i];
            float4 a1u = *(const float4*)(a1 + u * HEADS);
            s0 += __expf(lrelu(a1u.x + a2v.x) - m0);
            s1 += __expf(lrelu(a1u.y + a2v.y) - m1);
            s2 += __expf(lrelu(a1u.z + a2v.z) - m2);
            s3 += __expf(lrelu(a1u.w + a2v.w) - m3);
        }
        #pragma unroll
        for (int off = 1; off < 64; off <<= 1) {
            s0 += __shfl_xor(s0, off);
            s1 += __shfl_xor(s1, off);
            s2 += __shfl_xor(s2, off);
            s3 += __shfl_xor(s3, off);
        }
        float a2h = (h < 2) ? (h == 0 ? a2v.x : a2v.y) : (h == 2 ? a2v.z : a2v.w);
        float mh  = (h < 2) ? (h == 0 ? m0 : m1) : (h == 2 ? m2 : m3);
        float dh  = (h < 2) ? (h == 0 ? s0 : s1) : (h == 2 ? s2 : s3);
        float rdh = 1.0f / dh;
        for (int i = beg; i < end; ++i) {
            int u = csr_src[i];
            float a1h = a1[u * HEADS + h];
            float alpha = __expf(lrelu(a1h + a2h) - mh) * rdh;
            __half2 hv = *(const __half2*)(ft + (size_t)u * FDIM + f);
            float2 fv = __half22float2(hv);
            acc.x = fmaf(alpha, fv.x, acc.x);
            acc.y = fmaf(alpha, fv.y, acc.y);
        }
    }
    float2 o;
    o.x = fmaxf(acc.x, 0.f);
    o.y = fmaxf(acc.y, 0.f);
    *(float2*)(out + (size_t)v * FDIM + f) = o;
}

// ---------------- layer 2: h @ W2 (W2 staged in LDS) + attention coeffs ----------------
__global__ __launch_bounds__(256) void k_layer2(const float* __restrict__ hin,
        const float* __restrict__ W2, const float* __restrict__ al,
        const float* __restrict__ ar, __half* __restrict__ ft,
        float* __restrict__ a1, float* __restrict__ a2, int n) {
    __shared__ float wlds[64 * FDIM];   // 32 KB K-chunk of W2
    int tid = threadIdx.x, lane = tid & 63, w = tid >> 6;
    int wave = blockIdx.x * 4 + w;
    int v0 = wave * NPW;
    int f = 2 * lane;
    float2 acc[NPW];
    #pragma unroll
    for (int j = 0; j < NPW; ++j) acc[j] = make_float2(0.f, 0.f);
    for (int kc = 0; kc < FDIM; kc += 64) {
        __syncthreads();
        #pragma unroll
        for (int t = 0; t < (64 * FDIM / 4) / 256; ++t) {
            int idx = t * 256 + tid;
            ((float4*)wlds)[idx] = ((const float4*)(W2 + kc * FDIM))[idx];
        }
        __syncthreads();
        float hreg[NPW];
        #pragma unroll
        for (int j = 0; j < NPW; ++j) {
            int v = v0 + j; if (v >= n) v = n - 1;
            hreg[j] = hin[(size_t)v * FDIM + kc + lane];   // coalesced
        }
        #pragma unroll 8
        for (int k = 0; k < 64; ++k) {
            float2 wv = *(const float2*)(wlds + k * FDIM + f);
            #pragma unroll
            for (int j = 0; j < NPW; ++j) {
                float hk = rdlanef(hreg[j], k);
                acc[j].x += hk * wv.x;
                acc[j].y += hk * wv.y;
            }
        }
    }
    float2 alv = *(const float2*)(al + f);
    float2 arv = *(const float2*)(ar + f);
    int h = lane >> 4;
    #pragma unroll
    for (int j = 0; j < NPW; ++j) {
        int v = v0 + j;
        if (v < n) *(__half2*)(ft + (size_t)v * FDIM + f) = __floats2half2_rn(acc[j].x, acc[j].y);
        float s1 = acc[j].x * alv.x + acc[j].y * alv.y;
        float s2 = acc[j].x * arv.x + acc[j].y * arv.y;
        #pragma unroll
        for (int off = 1; off < 16; off <<= 1) {
            s1 += __shfl_xor(s1, off);
            s2 += __shfl_xor(s2, off);
        }
        if (v < n && (lane & 15) == 0) {
            a1[v * HEADS + h] = s1;
            a2[v * HEADS + h] = s2;
        }
    }
}

// ---------------- per-graph mean pooling (run-length + atomics) ----------------
__global__ void k_pool(const float* __restrict__ h, const int* __restrict__ gid,
                       float* __restrict__ gsum, int* __restrict__ gcnt, int n) {
    const int STRIP = 32;
    int wv = (blockIdx.x * blockDim.x + threadIdx.x) >> 6;
    int lane = threadIdx.x & 63;
    int beg = wv * STRIP;
    if (beg >= n) return;
    int end = min(beg + STRIP, n);
    int f = 2 * lane;
    float2 acc = make_float2(0.f, 0.f);
    int cur = gid[beg];
    int cnt = 0;
    for (int i = beg; i < end; ++i) {
        int g = gid[i];
        if (g != cur) {
            atomicAdd(&gsum[cur * FDIM + f], acc.x);
            atomicAdd(&gsum[cur * FDIM + f + 1], acc.y);
            if (lane == 0) atomicAdd(&gcnt[cur], cnt);
            acc = make_float2(0.f, 0.f); cnt = 0; cur = g;
        }
        float2 x = *(const float2*)(h + (size_t)i * FDIM + f);
        acc.x += x.x; acc.y += x.y; cnt++;
    }
    atomicAdd(&gsum[cur * FDIM + f], acc.x);
    atomicAdd(&gsum[cur * FDIM + f + 1], acc.y);
    if (lane == 0) atomicAdd(&gcnt[cur], cnt);
}

// ---------------- classifier ----------------
__global__ void k_classify(const float* __restrict__ gsum, const int* __restrict__ gcnt,
                           const float* __restrict__ Wc, const float* __restrict__ bc,
                           float* __restrict__ out) {
    int idx = blockIdx.x * blockDim.x + threadIdx.x;
    if (idx >= NGRAPH * NCLASS) return;
    int g = idx / NCLASS, c = idx % NCLASS;
    float rc = 1.0f / fmaxf((float)gcnt[g], 1.0f);
    float s = bc[c];
    for (int k = 0; k < FDIM; ++k)
        s += gsum[g * FDIM + k] * rc * Wc[k * NCLASS + c];
    out[idx] = 1.0f / (1.0f + __expf(-s));
}

extern "C" void kernel_launch(void* const* d_in, const int* in_sizes, int n_in,
                              void* d_out, int out_size, void* d_ws, size_t ws_size,
                              hipStream_t stream) {
    const int*   src = (const int*)d_in[0];
    const int*   dst = (const int*)d_in[1];
    const int*   gid = (const int*)d_in[2];
    const float* W1  = (const float*)d_in[3];
    const float* al1 = (const float*)d_in[4];
    const float* ar1 = (const float*)d_in[5];
    const float* W2  = (const float*)d_in[6];
    const float* al2 = (const float*)d_in[7];
    const float* ar2 = (const float*)d_in[8];
    const float* Wc  = (const float*)d_in[9];
    const float* bc  = (const float*)d_in[10];
    float* out = (float*)d_out;
    const int E = in_sizes[0];
    const int N = in_sizes[2];

    char* ws = (char*)d_ws;
    size_t off = 0;
    auto alloc = [&](size_t bytes) -> void* {
        void* p = ws + off;
        off = (off + bytes + 255) & ~(size_t)255;
        return p;
    };
    int*    deg    = (int*)alloc((size_t)N * 4);
    int*    offs   = (int*)alloc((size_t)(N + 1) * 4);
    int*    cursor = (int*)alloc((size_t)N * 4);
    int*    csr    = (int*)alloc((size_t)E * 4);
    int*    bsum   = (int*)alloc((size_t)((N + 1023) / 1024) * 4);
    float*  a1     = (float*)alloc((size_t)N * HEADS * 4);
    float*  a2     = (float*)alloc((size_t)N * HEADS * 4);
    __half* ft16   = (__half*)alloc((size_t)N * FDIM * 2);
    float*  hbuf   = (float*)alloc((size_t)N * FDIM * 4);
    float*  gsum   = (float*)alloc((size_t)NGRAPH * FDIM * 4);
    int*    gcnt   = (int*)alloc((size_t)NGRAPH * 4);

    hipMemsetAsync(deg, 0, (size_t)N * 4, stream);
    hipMemsetAsync(cursor, 0, (size_t)N * 4, stream);
    hipMemsetAsync(gsum, 0, (size_t)NGRAPH * FDIM * 4, stream);
    hipMemsetAsync(gcnt, 0, (size_t)NGRAPH * 4, stream);

    int eb = (E + 255) / 256;
    int nb = (N + 1023) / 1024;
    k_hist<<<eb, 256, 0, stream>>>(dst, deg, E);
    k_bsum<<<nb, 256, 0, stream>>>(deg, bsum, N);
    k_bscan<<<1, 64, 0, stream>>>(bsum, nb, offs, N, E);
    k_offs<<<nb, 256, 0, stream>>>(deg, bsum, offs, N);
    k_scatter<<<eb, 256, 0, stream>>>(src, dst, offs, cursor, csr, E);

    int nwb = (N + 3) / 4;   // wave-per-node kernels: 4 waves / 256-thread block
    k_layer1<<<nwb, 256, 0, stream>>>(deg, W1, al1, ar1, ft16, a1, a2, N);
    k_aggregate<<<nwb, 256, 0, stream>>>(offs, csr, ft16, a1, a2, hbuf, N);
    int l2b = (N + NPW * 4 - 1) / (NPW * 4);
    k_layer2<<<l2b, 256, 0, stream>>>(hbuf, W2, al2, ar2, ft16, a1, a2, N);
    k_aggregate<<<nwb, 256, 0, stream>>>(offs, csr, ft16, a1, a2, hbuf, N);

    int pb = (((N + 31) / 32) + 3) / 4;
    k_pool<<<pb, 256, 0, stream>>>(hbuf, gid, gsum, gcnt, N);
    k_classify<<<(NGRAPH * NCLASS + 255) / 256, 256, 0, stream>>>(gsum, gcnt, Wc, bc, out);
}

// Round 3
// 221.224 us; speedup vs baseline: 1.8934x; 1.3921x over previous
//
#include <hip/hip_runtime.h>
#include <hip/hip_fp16.h>
#include <math.h>

#define HEADS 4
#define HDIM 32
#define FDIM 128   // HEADS*HDIM
#define NGRAPH 128
#define NCLASS 10
#define NPW 8      // nodes per wave in layer-2 GEMM

__device__ __forceinline__ float lrelu(float x) { return fmaxf(x, 0.2f * x); }

// ---------------- histogram of dst (in-degree) ----------------
__global__ void k_hist(const int* __restrict__ dst, int* __restrict__ deg, int E) {
    int i = blockIdx.x * blockDim.x + threadIdx.x;
    if (i < E) atomicAdd(&deg[dst[i]], 1);
}

// ---------------- scan step 1: per-block (1024 elems) sums ----------------
__global__ void k_bsum(const int* __restrict__ deg, int* __restrict__ bsum, int n) {
    int tid = threadIdx.x, lane = tid & 63, w = tid >> 6;
    int base = blockIdx.x * 1024 + tid * 4;
    int t = 0;
    #pragma unroll
    for (int k = 0; k < 4; ++k) {
        int i = base + k;
        if (i < n) t += deg[i];
    }
    #pragma unroll
    for (int off = 1; off < 64; off <<= 1) t += __shfl_xor(t, off);
    __shared__ int ws[4];
    if (lane == 0) ws[w] = t;
    __syncthreads();
    if (tid == 0) bsum[blockIdx.x] = ws[0] + ws[1] + ws[2] + ws[3];
}

// ---------------- scan step 2: exclusive scan of block sums (1 wave) ----------------
__global__ void k_bscan(int* __restrict__ bsum, int nb, int* __restrict__ offs,
                        int n, int E) {
    int lane = threadIdx.x;
    int carry = 0;
    for (int base = 0; base < nb; base += 64) {
        int i = base + lane;
        int v = (i < nb) ? bsum[i] : 0;
        int p = v;
        #pragma unroll
        for (int off = 1; off < 64; off <<= 1) {
            int y = __shfl_up(p, off);
            if (lane >= off) p += y;
        }
        if (i < nb) bsum[i] = carry + p - v;   // exclusive
        carry += __shfl(p, 63);
    }
    if (lane == 0) offs[n] = E;
}

// ---------------- scan step 3: per-block exclusive offsets (+zero cursor/gsum/gcnt) ----------------
__global__ void k_offs(const int* __restrict__ deg, const int* __restrict__ boff,
                       int* __restrict__ offs, int* __restrict__ cursor,
                       float* __restrict__ gsum, int* __restrict__ gcnt, int n) {
    int tid = threadIdx.x, lane = tid & 63, w = tid >> 6;
    int gtid = blockIdx.x * 256 + tid;
    if (gtid < NGRAPH * FDIM / 4) ((float4*)gsum)[gtid] = make_float4(0.f, 0.f, 0.f, 0.f);
    if (gtid < NGRAPH) gcnt[gtid] = 0;
    int base = blockIdx.x * 1024 + tid * 4;
    int v[4]; int t = 0;
    #pragma unroll
    for (int k = 0; k < 4; ++k) {
        int i = base + k;
        v[k] = (i < n) ? deg[i] : 0;
        if (i < n) cursor[i] = 0;
        t += v[k];
    }
    int incl = t;
    #pragma unroll
    for (int off = 1; off < 64; off <<= 1) {
        int y = __shfl_up(incl, off);
        if (lane >= off) incl += y;
    }
    int lpre = incl - t;
    __shared__ int ws[4];
    if (lane == 63) ws[w] = incl;
    __syncthreads();
    int wpre = 0;
    #pragma unroll
    for (int j = 0; j < 4; ++j) if (j < w) wpre += ws[j];
    int g = boff[blockIdx.x] + wpre + lpre;
    #pragma unroll
    for (int k = 0; k < 4; ++k) {
        int i = base + k;
        if (i < n) offs[i] = g;
        g += v[k];
    }
}

// ---------------- CSR scatter (store src per slot) ----------------
__global__ void k_scatter(const int* __restrict__ src, const int* __restrict__ dst,
                          const int* __restrict__ offs, int* __restrict__ cursor,
                          int* __restrict__ csr_src, int E) {
    int i = blockIdx.x * blockDim.x + threadIdx.x;
    if (i < E) {
        int d = dst[i];
        int p = atomicAdd(&cursor[d], 1);
        csr_src[offs[d] + p] = src[i];
    }
}

// ---------------- layer-1 node features + attention coefficients ----------------
// h4[v] = (deg, deg>3, 3/deg, deg>4); a1[v,h] = h4 . (W1 al_h); a2 likewise.
__global__ void k_atts1(const int* __restrict__ deg, const float* __restrict__ W1,
                        const float* __restrict__ al, const float* __restrict__ ar,
                        float* __restrict__ h4t, float* __restrict__ a1,
                        float* __restrict__ a2, int n) {
    __shared__ float wla[16], wlr[16];   // [k*4 + h]
    int tid = threadIdx.x;
    if (tid < 32) {
        int k = (tid & 15) >> 2, h = tid & 3;
        const float* av = (tid < 16) ? al : ar;
        float s = 0.f;
        #pragma unroll
        for (int d = 0; d < 32; ++d) s += W1[k * FDIM + h * HDIM + d] * av[h * HDIM + d];
        if (tid < 16) wla[k * 4 + h] = s; else wlr[k * 4 + h] = s;
    }
    __syncthreads();
    int v = blockIdx.x * blockDim.x + tid;
    if (v >= n) return;
    float d = (float)deg[v];
    float4 hv = make_float4(d, (d - 3.0f > 0.0f) ? 1.0f : 0.0f, 3.0f / d,
                            (d - 4.0f > 0.0f) ? 1.0f : 0.0f);
    *(float4*)(h4t + v * 4) = hv;
    float4 o1, o2;
    #pragma unroll
    for (int h = 0; h < 4; ++h) {
        float s1 = hv.x * wla[0 + h] + hv.y * wla[4 + h] + hv.z * wla[8 + h] + hv.w * wla[12 + h];
        float s2 = hv.x * wlr[0 + h] + hv.y * wlr[4 + h] + hv.z * wlr[8 + h] + hv.w * wlr[12 + h];
        if (h == 0) { o1.x = s1; o2.x = s2; } else if (h == 1) { o1.y = s1; o2.y = s2; }
        else if (h == 2) { o1.z = s1; o2.z = s2; } else { o1.w = s1; o2.w = s2; }
    }
    *(float4*)(a1 + v * 4) = o1;
    *(float4*)(a2 + v * 4) = o2;
}

// ---------------- aggregate #1 in 4-dim feature space ----------------
// S[v][h*4+d] = sum_u alpha_{u,h} * h4[u][d]   (16 lanes per node)
__global__ void k_agg1(const int* __restrict__ offs, const int* __restrict__ csr,
                       const float* __restrict__ h4t, const float* __restrict__ a1,
                       const float* __restrict__ a2, float* __restrict__ S, int n) {
    int tid = threadIdx.x, lane = tid & 63, w = tid >> 6;
    int g = lane >> 4, e = lane & 15;
    int v = (blockIdx.x * 4 + w) * 4 + g;
    bool vok = v < n;
    int beg = 0, end = 0;
    if (vok) { beg = offs[v]; end = offs[v + 1]; }
    int deg = end - beg;
    float4 a2v = vok ? *(const float4*)(a2 + v * 4) : make_float4(0, 0, 0, 0);
    float P[4][4]; float D[4];
    #pragma unroll
    for (int h = 0; h < 4; ++h) { D[h] = 0.f;
        #pragma unroll
        for (int d = 0; d < 4; ++d) P[h][d] = 0.f; }
    for (int base = 0; base < deg; base += 16) {
        if (base + e < deg) {
            int u = csr[beg + base + e];
            float4 a1u = *(const float4*)(a1 + u * 4);
            float4 f4  = *(const float4*)(h4t + u * 4);
            float wgt[4];
            wgt[0] = __expf(lrelu(a1u.x + a2v.x));
            wgt[1] = __expf(lrelu(a1u.y + a2v.y));
            wgt[2] = __expf(lrelu(a1u.z + a2v.z));
            wgt[3] = __expf(lrelu(a1u.w + a2v.w));
            #pragma unroll
            for (int h = 0; h < 4; ++h) {
                D[h] += wgt[h];
                P[h][0] = fmaf(wgt[h], f4.x, P[h][0]);
                P[h][1] = fmaf(wgt[h], f4.y, P[h][1]);
                P[h][2] = fmaf(wgt[h], f4.z, P[h][2]);
                P[h][3] = fmaf(wgt[h], f4.w, P[h][3]);
            }
        }
    }
    #pragma unroll
    for (int off = 1; off < 16; off <<= 1) {
        #pragma unroll
        for (int h = 0; h < 4; ++h) {
            D[h] += __shfl_xor(D[h], off);
            #pragma unroll
            for (int d = 0; d < 4; ++d) P[h][d] += __shfl_xor(P[h][d], off);
        }
    }
    if (vok && e == 0) {
        #pragma unroll
        for (int h = 0; h < 4; ++h) {
            float r = 1.0f / D[h];
            *(float4*)(S + v * 16 + h * 4) =
                make_float4(P[h][0] * r, P[h][1] * r, P[h][2] * r, P[h][3] * r);
        }
    }
}

// ---------------- layer 2: h1 = relu(S@W1) on the fly; GEMM vs W2; attn coeffs ----------------
__global__ __launch_bounds__(256) void k_layer2(const float* __restrict__ S,
        const float* __restrict__ W1, const float* __restrict__ W2,
        const float* __restrict__ al, const float* __restrict__ ar,
        __half* __restrict__ ft, float* __restrict__ a1, float* __restrict__ a2, int n) {
    __shared__ float wlds[64 * FDIM];   // 32 KB K-chunk of W2
    int tid = threadIdx.x, lane = tid & 63, w = tid >> 6;
    int wave = blockIdx.x * 4 + w;
    int v0 = wave * NPW;
    int f = 2 * lane;
    float2 acc[NPW];
    #pragma unroll
    for (int j = 0; j < NPW; ++j) acc[j] = make_float2(0.f, 0.f);
    for (int kc = 0; kc < FDIM; kc += 64) {
        __syncthreads();
        #pragma unroll
        for (int t = 0; t < (64 * FDIM / 4) / 256; ++t) {
            int idx = t * 256 + tid;
            ((float4*)wlds)[idx] = ((const float4*)(W2 + kc * FDIM))[idx];
        }
        __syncthreads();
        // W1 column (kc+lane), 4 entries
        float w1c0 = W1[0 * FDIM + kc + lane];
        float w1c1 = W1[1 * FDIM + kc + lane];
        float w1c2 = W1[2 * FDIM + kc + lane];
        float w1c3 = W1[3 * FDIM + kc + lane];
        bool hi = lane >= 32;
        float hreg[NPW];
        #pragma unroll
        for (int j = 0; j < NPW; ++j) {
            int v = v0 + j; if (v >= n) v = n - 1;
            const float4* Sp = (const float4*)(S + v * 16 + (kc >> 3));
            float4 sa = Sp[0], sb = Sp[1];
            float4 sv;
            sv.x = hi ? sb.x : sa.x; sv.y = hi ? sb.y : sa.y;
            sv.z = hi ? sb.z : sa.z; sv.w = hi ? sb.w : sa.w;
            float t1 = sv.x * w1c0 + sv.y * w1c1 + sv.z * w1c2 + sv.w * w1c3;
            hreg[j] = fmaxf(t1, 0.f);
        }
        #pragma unroll 8
        for (int k = 0; k < 64; ++k) {
            float2 wv = *(const float2*)(wlds + k * FDIM + f);
            #pragma unroll
            for (int j = 0; j < NPW; ++j) {
                float hk = __int_as_float(__builtin_amdgcn_readlane(__float_as_int(hreg[j]), k));
                acc[j].x += hk * wv.x;
                acc[j].y += hk * wv.y;
            }
        }
    }
    float2 alv = *(const float2*)(al + f);
    float2 arv = *(const float2*)(ar + f);
    int h = lane >> 4;
    #pragma unroll
    for (int j = 0; j < NPW; ++j) {
        int v = v0 + j;
        if (v < n) *(__half2*)(ft + (size_t)v * FDIM + f) = __floats2half2_rn(acc[j].x, acc[j].y);
        float s1 = acc[j].x * alv.x + acc[j].y * alv.y;
        float s2 = acc[j].x * arv.x + acc[j].y * arv.y;
        #pragma unroll
        for (int off = 1; off < 16; off <<= 1) {
            s1 += __shfl_xor(s1, off);
            s2 += __shfl_xor(s2, off);
        }
        if (v < n && (lane & 15) == 0) {
            a1[v * HEADS + h] = s1;
            a2[v * HEADS + h] = s2;
        }
    }
}

// ---------------- aggregate #2: wave-per-node, no-max softmax, post-divide ----------------
__global__ void k_agg2(const int* __restrict__ offs, const int* __restrict__ csr,
                       const __half* __restrict__ ft, const float* __restrict__ a1,
                       const float* __restrict__ a2, __half* __restrict__ out, int n) {
    __shared__ float wlds[4][64 * 4];
    int tid = threadIdx.x, lane = tid & 63, w = tid >> 6;
    int v = blockIdx.x * 4 + w;
    if (v >= n) return;
    int beg = offs[v], end = offs[v + 1];
    int deg = end - beg;
    float4 a2v = *(const float4*)(a2 + v * 4);
    int h = lane >> 4;
    int f = 2 * lane;
    float2 acc = make_float2(0.f, 0.f);
    float4 dsum = make_float4(0.f, 0.f, 0.f, 0.f);
    float* wbuf = wlds[w];
    for (int base = 0; base < deg; base += 64) {
        int m = min(64, deg - base);
        int u = 0;
        float4 wgt = make_float4(0.f, 0.f, 0.f, 0.f);
        if (lane < m) {
            u = csr[beg + base + lane];
            float4 a1u = *(const float4*)(a1 + u * 4);
            wgt.x = __expf(lrelu(a1u.x + a2v.x));
            wgt.y = __expf(lrelu(a1u.y + a2v.y));
            wgt.z = __expf(lrelu(a1u.z + a2v.z));
            wgt.w = __expf(lrelu(a1u.w + a2v.w));
        }
        dsum.x += wgt.x; dsum.y += wgt.y; dsum.z += wgt.z; dsum.w += wgt.w;
        *(float4*)(wbuf + lane * 4) = wgt;
        int j = 0;
        for (; j + 4 <= m; j += 4) {
            int s0 = __builtin_amdgcn_readlane(u, j);
            int s1 = __builtin_amdgcn_readlane(u, j + 1);
            int s2 = __builtin_amdgcn_readlane(u, j + 2);
            int s3 = __builtin_amdgcn_readlane(u, j + 3);
            float w0 = wbuf[(j + 0) * 4 + h];
            float w1 = wbuf[(j + 1) * 4 + h];
            float w2 = wbuf[(j + 2) * 4 + h];
            float w3 = wbuf[(j + 3) * 4 + h];
            float2 g0 = __half22float2(*(const __half2*)(ft + (size_t)s0 * FDIM + f));
            float2 g1 = __half22float2(*(const __half2*)(ft + (size_t)s1 * FDIM + f));
            float2 g2 = __half22float2(*(const __half2*)(ft + (size_t)s2 * FDIM + f));
            float2 g3 = __half22float2(*(const __half2*)(ft + (size_t)s3 * FDIM + f));
            acc.x = fmaf(w0, g0.x, acc.x); acc.y = fmaf(w0, g0.y, acc.y);
            acc.x = fmaf(w1, g1.x, acc.x); acc.y = fmaf(w1, g1.y, acc.y);
            acc.x = fmaf(w2, g2.x, acc.x); acc.y = fmaf(w2, g2.y, acc.y);
            acc.x = fmaf(w3, g3.x, acc.x); acc.y = fmaf(w3, g3.y, acc.y);
        }
        for (; j < m; ++j) {
            int s0 = __builtin_amdgcn_readlane(u, j);
            float w0 = wbuf[j * 4 + h];
            float2 g0 = __half22float2(*(const __half2*)(ft + (size_t)s0 * FDIM + f));
            acc.x = fmaf(w0, g0.x, acc.x); acc.y = fmaf(w0, g0.y, acc.y);
        }
    }
    #pragma unroll
    for (int off = 1; off < 64; off <<= 1) {
        dsum.x += __shfl_xor(dsum.x, off);
        dsum.y += __shfl_xor(dsum.y, off);
        dsum.z += __shfl_xor(dsum.z, off);
        dsum.w += __shfl_xor(dsum.w, off);
    }
    float dh = (h < 2) ? (h == 0 ? dsum.x : dsum.y) : (h == 2 ? dsum.z : dsum.w);
    float r = 1.0f / dh;
    *(__half2*)(out + (size_t)v * FDIM + f) =
        __floats2half2_rn(fmaxf(acc.x * r, 0.f), fmaxf(acc.y * r, 0.f));
}

// ---------------- per-graph mean pooling (run-length + atomics) ----------------
__global__ void k_pool(const __half* __restrict__ hbuf, const int* __restrict__ gid,
                       float* __restrict__ gsum, int* __restrict__ gcnt, int n) {
    const int STRIP = 32;
    int wv = (blockIdx.x * blockDim.x + threadIdx.x) >> 6;
    int lane = threadIdx.x & 63;
    int beg = wv * STRIP;
    if (beg >= n) return;
    int end = min(beg + STRIP, n);
    int f = 2 * lane;
    float2 acc = make_float2(0.f, 0.f);
    int cur = gid[beg];
    int cnt = 0;
    for (int i = beg; i < end; ++i) {
        int g = gid[i];
        if (g != cur) {
            atomicAdd(&gsum[cur * FDIM + f], acc.x);
            atomicAdd(&gsum[cur * FDIM + f + 1], acc.y);
            if (lane == 0) atomicAdd(&gcnt[cur], cnt);
            acc = make_float2(0.f, 0.f); cnt = 0; cur = g;
        }
        float2 x = __half22float2(*(const __half2*)(hbuf + (size_t)i * FDIM + f));
        acc.x += x.x; acc.y += x.y; cnt++;
    }
    atomicAdd(&gsum[cur * FDIM + f], acc.x);
    atomicAdd(&gsum[cur * FDIM + f + 1], acc.y);
    if (lane == 0) atomicAdd(&gcnt[cur], cnt);
}

// ---------------- classifier ----------------
__global__ void k_classify(const float* __restrict__ gsum, const int* __restrict__ gcnt,
                           const float* __restrict__ Wc, const float* __restrict__ bc,
                           float* __restrict__ out) {
    int idx = blockIdx.x * blockDim.x + threadIdx.x;
    if (idx >= NGRAPH * NCLASS) return;
    int g = idx / NCLASS, c = idx % NCLASS;
    float rc = 1.0f / fmaxf((float)gcnt[g], 1.0f);
    float s = bc[c];
    for (int k = 0; k < FDIM; ++k)
        s += gsum[g * FDIM + k] * rc * Wc[k * NCLASS + c];
    out[idx] = 1.0f / (1.0f + __expf(-s));
}

extern "C" void kernel_launch(void* const* d_in, const int* in_sizes, int n_in,
                              void* d_out, int out_size, void* d_ws, size_t ws_size,
                              hipStream_t stream) {
    const int*   src = (const int*)d_in[0];
    const int*   dst = (const int*)d_in[1];
    const int*   gid = (const int*)d_in[2];
    const float* W1  = (const float*)d_in[3];
    const float* al1 = (const float*)d_in[4];
    const float* ar1 = (const float*)d_in[5];
    const float* W2  = (const float*)d_in[6];
    const float* al2 = (const float*)d_in[7];
    const float* ar2 = (const float*)d_in[8];
    const float* Wc  = (const float*)d_in[9];
    const float* bc  = (const float*)d_in[10];
    float* out = (float*)d_out;
    const int E = in_sizes[0];
    const int N = in_sizes[2];

    char* ws = (char*)d_ws;
    size_t off = 0;
    auto alloc = [&](size_t bytes) -> void* {
        void* p = ws + off;
        off = (off + bytes + 255) & ~(size_t)255;
        return p;
    };
    int*    deg    = (int*)alloc((size_t)N * 4);
    int*    offs   = (int*)alloc((size_t)(N + 1) * 4);
    int*    cursor = (int*)alloc((size_t)N * 4);
    int*    csr    = (int*)alloc((size_t)E * 4);
    int*    bsum   = (int*)alloc((size_t)((N + 1023) / 1024) * 4);
    float*  h4t    = (float*)alloc((size_t)N * 4 * 4);
    float*  a1     = (float*)alloc((size_t)N * HEADS * 4);
    float*  a2     = (float*)alloc((size_t)N * HEADS * 4);
    float*  Sbuf   = (float*)alloc((size_t)N * 16 * 4);
    __half* ft16   = (__half*)alloc((size_t)N * FDIM * 2);
    __half* hbuf   = (__half*)alloc((size_t)N * FDIM * 2);
    float*  gsum   = (float*)alloc((size_t)NGRAPH * FDIM * 4);
    int*    gcnt   = (int*)alloc((size_t)NGRAPH * 4);

    hipMemsetAsync(deg, 0, (size_t)N * 4, stream);

    int eb = (E + 255) / 256;
    int nb = (N + 1023) / 1024;
    k_hist<<<eb, 256, 0, stream>>>(dst, deg, E);
    k_bsum<<<nb, 256, 0, stream>>>(deg, bsum, N);
    k_bscan<<<1, 64, 0, stream>>>(bsum, nb, offs, N, E);
    k_offs<<<nb, 256, 0, stream>>>(deg, bsum, offs, cursor, gsum, gcnt, N);
    k_scatter<<<eb, 256, 0, stream>>>(src, dst, offs, cursor, csr, E);

    k_atts1<<<(N + 255) / 256, 256, 0, stream>>>(deg, W1, al1, ar1, h4t, a1, a2, N);
    k_agg1<<<(N + 15) / 16, 256, 0, stream>>>(offs, csr, h4t, a1, a2, Sbuf, N);
    int l2b = (N + NPW * 4 - 1) / (NPW * 4);
    k_layer2<<<l2b, 256, 0, stream>>>(Sbuf, W1, W2, al2, ar2, ft16, a1, a2, N);
    k_agg2<<<(N + 3) / 4, 256, 0, stream>>>(offs, csr, ft16, a1, a2, hbuf, N);

    int pb = (((N + 31) / 32) + 3) / 4;
    k_pool<<<pb, 256, 0, stream>>>(hbuf, gid, gsum, gcnt, N);
    k_classify<<<(NGRAPH * NCLASS + 255) / 256, 256, 0, stream>>>(gsum, gcnt, Wc, bc, out);
}

// Round 5
// 194.782 us; speedup vs baseline: 2.1504x; 1.1358x over previous
//
#include <hip/hip_runtime.h>
#include <hip/hip_fp16.h>
#include <math.h>

#define HEADS 4
#define HDIM 32
#define FDIM 128   // HEADS*HDIM
#define NGRAPH 128
#define NCLASS 10

typedef _Float16 h4_t __attribute__((ext_vector_type(4)));
typedef float f4_t __attribute__((ext_vector_type(4)));

__device__ __forceinline__ float lrelu(float x) { return fmaxf(x, 0.2f * x); }

// ---------------- histogram of dst (in-degree) ----------------
__global__ void k_hist(const int* __restrict__ dst, int* __restrict__ deg, int E) {
    int i = blockIdx.x * blockDim.x + threadIdx.x;
    if (i < E) atomicAdd(&deg[dst[i]], 1);
}

// ---------------- scan step 1: per-block (1024 elems) sums ----------------
__global__ void k_bsum(const int* __restrict__ deg, int* __restrict__ bsum, int n) {
    int tid = threadIdx.x, lane = tid & 63, w = tid >> 6;
    int base = blockIdx.x * 1024 + tid * 4;
    int t = 0;
    #pragma unroll
    for (int k = 0; k < 4; ++k) {
        int i = base + k;
        if (i < n) t += deg[i];
    }
    #pragma unroll
    for (int off = 1; off < 64; off <<= 1) t += __shfl_xor(t, off);
    __shared__ int ws[4];
    if (lane == 0) ws[w] = t;
    __syncthreads();
    if (tid == 0) bsum[blockIdx.x] = ws[0] + ws[1] + ws[2] + ws[3];
}

// ---------------- scan step 2: exclusive scan of block sums (1 wave) ----------------
__global__ void k_bscan(int* __restrict__ bsum, int nb, int* __restrict__ offs,
                        int n, int E) {
    int lane = threadIdx.x;
    int carry = 0;
    for (int base = 0; base < nb; base += 64) {
        int i = base + lane;
        int v = (i < nb) ? bsum[i] : 0;
        int p = v;
        #pragma unroll
        for (int off = 1; off < 64; off <<= 1) {
            int y = __shfl_up(p, off);
            if (lane >= off) p += y;
        }
        if (i < nb) bsum[i] = carry + p - v;   // exclusive
        carry += __shfl(p, 63);
    }
    if (lane == 0) offs[n] = E;
}

// ---------------- scan step 3: per-block exclusive offsets (+zero cursor/gsum/gcnt) ----------------
__global__ void k_offs(const int* __restrict__ deg, const int* __restrict__ boff,
                       int* __restrict__ offs, int* __restrict__ cursor,
                       float* __restrict__ gsum, int* __restrict__ gcnt, int n) {
    int tid = threadIdx.x, lane = tid & 63, w = tid >> 6;
    int gtid = blockIdx.x * 256 + tid;
    if (gtid < NGRAPH * FDIM / 4) ((float4*)gsum)[gtid] = make_float4(0.f, 0.f, 0.f, 0.f);
    if (gtid < NGRAPH) gcnt[gtid] = 0;
    int base = blockIdx.x * 1024 + tid * 4;
    int v[4]; int t = 0;
    #pragma unroll
    for (int k = 0; k < 4; ++k) {
        int i = base + k;
        v[k] = (i < n) ? deg[i] : 0;
        if (i < n) cursor[i] = 0;
        t += v[k];
    }
    int incl = t;
    #pragma unroll
    for (int off = 1; off < 64; off <<= 1) {
        int y = __shfl_up(incl, off);
        if (lane >= off) incl += y;
    }
    int lpre = incl - t;
    __shared__ int ws[4];
    if (lane == 63) ws[w] = incl;
    __syncthreads();
    int wpre = 0;
    #pragma unroll
    for (int j = 0; j < 4; ++j) if (j < w) wpre += ws[j];
    int g = boff[blockIdx.x] + wpre + lpre;
    #pragma unroll
    for (int k = 0; k < 4; ++k) {
        int i = base + k;
        if (i < n) offs[i] = g;
        g += v[k];
    }
}

// ---------------- CSR scatter (store src per slot) ----------------
__global__ void k_scatter(const int* __restrict__ src, const int* __restrict__ dst,
                          const int* __restrict__ offs, int* __restrict__ cursor,
                          int* __restrict__ csr_src, int E) {
    int i = blockIdx.x * blockDim.x + threadIdx.x;
    if (i < E) {
        int d = dst[i];
        int p = atomicAdd(&cursor[d], 1);
        csr_src[offs[d] + p] = src[i];
    }
}

// ---------------- layer-1 node features + attention coefficients ----------------
__global__ void k_atts1(const int* __restrict__ deg, const float* __restrict__ W1,
                        const float* __restrict__ al, const float* __restrict__ ar,
                        float* __restrict__ h4t, float* __restrict__ a1,
                        float* __restrict__ a2, int n) {
    __shared__ float wla[16], wlr[16];   // [k*4 + h]
    int tid = threadIdx.x;
    if (tid < 32) {
        int k = (tid & 15) >> 2, h = tid & 3;
        const float* av = (tid < 16) ? al : ar;
        float s = 0.f;
        #pragma unroll
        for (int d = 0; d < 32; ++d) s += W1[k * FDIM + h * HDIM + d] * av[h * HDIM + d];
        if (tid < 16) wla[k * 4 + h] = s; else wlr[k * 4 + h] = s;
    }
    __syncthreads();
    int v = blockIdx.x * blockDim.x + tid;
    if (v >= n) return;
    float d = (float)deg[v];
    float4 hv = make_float4(d, (d - 3.0f > 0.0f) ? 1.0f : 0.0f, 3.0f / d,
                            (d - 4.0f > 0.0f) ? 1.0f : 0.0f);
    *(float4*)(h4t + v * 4) = hv;
    float4 o1, o2;
    #pragma unroll
    for (int h = 0; h < 4; ++h) {
        float s1 = hv.x * wla[0 + h] + hv.y * wla[4 + h] + hv.z * wla[8 + h] + hv.w * wla[12 + h];
        float s2 = hv.x * wlr[0 + h] + hv.y * wlr[4 + h] + hv.z * wlr[8 + h] + hv.w * wlr[12 + h];
        if (h == 0) { o1.x = s1; o2.x = s2; } else if (h == 1) { o1.y = s1; o2.y = s2; }
        else if (h == 2) { o1.z = s1; o2.z = s2; } else { o1.w = s1; o2.w = s2; }
    }
    *(float4*)(a1 + v * 4) = o1;
    *(float4*)(a2 + v * 4) = o2;
}

// ---------------- aggregate #1 in 4-dim feature space ----------------
__global__ void k_agg1(const int* __restrict__ offs, const int* __restrict__ csr,
                       const float* __restrict__ h4t, const float* __restrict__ a1,
                       const float* __restrict__ a2, float* __restrict__ S, int n) {
    int tid = threadIdx.x, lane = tid & 63, w = tid >> 6;
    int g = lane >> 4, e = lane & 15;
    int v = (blockIdx.x * 4 + w) * 4 + g;
    bool vok = v < n;
    int beg = 0, end = 0;
    if (vok) { beg = offs[v]; end = offs[v + 1]; }
    int deg = end - beg;
    float4 a2v = vok ? *(const float4*)(a2 + v * 4) : make_float4(0, 0, 0, 0);
    float P[4][4]; float D[4];
    #pragma unroll
    for (int h = 0; h < 4; ++h) { D[h] = 0.f;
        #pragma unroll
        for (int d = 0; d < 4; ++d) P[h][d] = 0.f; }
    for (int base = 0; base < deg; base += 16) {
        if (base + e < deg) {
            int u = csr[beg + base + e];
            float4 a1u = *(const float4*)(a1 + u * 4);
            float4 f4  = *(const float4*)(h4t + u * 4);
            float wgt[4];
            wgt[0] = __expf(lrelu(a1u.x + a2v.x));
            wgt[1] = __expf(lrelu(a1u.y + a2v.y));
            wgt[2] = __expf(lrelu(a1u.z + a2v.z));
            wgt[3] = __expf(lrelu(a1u.w + a2v.w));
            #pragma unroll
            for (int h = 0; h < 4; ++h) {
                D[h] += wgt[h];
                P[h][0] = fmaf(wgt[h], f4.x, P[h][0]);
                P[h][1] = fmaf(wgt[h], f4.y, P[h][1]);
                P[h][2] = fmaf(wgt[h], f4.z, P[h][2]);
                P[h][3] = fmaf(wgt[h], f4.w, P[h][3]);
            }
        }
    }
    #pragma unroll
    for (int off = 1; off < 16; off <<= 1) {
        #pragma unroll
        for (int h = 0; h < 4; ++h) {
            D[h] += __shfl_xor(D[h], off);
            #pragma unroll
            for (int d = 0; d < 4; ++d) P[h][d] += __shfl_xor(P[h][d], off);
        }
    }
    if (vok && e == 0) {
        #pragma unroll
        for (int h = 0; h < 4; ++h) {
            float r = 1.0f / D[h];
            *(float4*)(S + v * 16 + h * 4) =
                make_float4(P[h][0] * r, P[h][1] * r, P[h][2] * r, P[h][3] * r);
        }
    }
}

// ---------------- W2 -> fp16 fragments in MFMA lane order ----------------
// frag fid = ks*8 + t; lane l holds B[k][n]: n = t*16 + (l&15), k = ks*16 + 4*(l>>4) + j
__global__ void k_wfrag(const float* __restrict__ W2, __half* __restrict__ Wfrag) {
    int gid = blockIdx.x * 256 + threadIdx.x;   // 4096 threads
    int fid = gid >> 6, l = gid & 63;
    int ks = fid >> 3, t = fid & 7;
    int k0 = ks * 16 + 4 * (l >> 4);
    int n0 = t * 16 + (l & 15);
    __half2 lo = __floats2half2_rn(W2[(k0 + 0) * FDIM + n0], W2[(k0 + 1) * FDIM + n0]);
    __half2 hi = __floats2half2_rn(W2[(k0 + 2) * FDIM + n0], W2[(k0 + 3) * FDIM + n0]);
    size_t base = ((size_t)fid * 64 + l) * 4;
    *(__half2*)(Wfrag + base)     = lo;
    *(__half2*)(Wfrag + base + 2) = hi;
}

// ---------------- layer 2 via MFMA: ft = relu(S@W1) @ W2, + attn coeffs ----------------
__global__ __launch_bounds__(256) void k_layer2(const float* __restrict__ S,
        const float* __restrict__ W1, const __half* __restrict__ Wfrag,
        const float* __restrict__ al, const float* __restrict__ ar,
        __half* __restrict__ ft, float* __restrict__ a1, float* __restrict__ a2, int n) {
    __shared__ __half Blds[64 * 64 * 4];        // 32 KB: 64 frags x 64 lanes x 4 halves
    __shared__ __half Alds[4][16 * 132];        // per-wave 16 nodes x 128 k, pitch 132
    int tid = threadIdx.x, l = tid & 63, w = tid >> 6;
    int c = l & 15, g = l >> 4;

    // stage W2 fragments: pure coalesced 32 KB copy
    #pragma unroll
    for (int i = 0; i < 8; ++i)
        ((float4*)Blds)[i * 256 + tid] = ((const float4*)Wfrag)[i * 256 + tid];

    // compute h1 = relu(S@W1) for this wave's 16 nodes into the A tile (fp16)
    int v0 = (blockIdx.x * 4 + w) * 16;
    float2 w1c[4];
    #pragma unroll
    for (int d = 0; d < 4; ++d) w1c[d] = *(const float2*)(W1 + d * FDIM + 2 * l);
    for (int jj = 0; jj < 16; ++jj) {
        int v = min(v0 + jj, n - 1);
        float4 s = *(const float4*)(S + v * 16 + g * 4);
        float t0 = s.x * w1c[0].x + s.y * w1c[1].x + s.z * w1c[2].x + s.w * w1c[3].x;
        float t1 = s.x * w1c[0].y + s.y * w1c[1].y + s.z * w1c[2].y + s.w * w1c[3].y;
        *(__half2*)(&Alds[w][jj * 132 + 2 * l]) = __floats2half2_rn(fmaxf(t0, 0.f), fmaxf(t1, 0.f));
    }
    __syncthreads();

    f4_t acc[8];
    #pragma unroll
    for (int t = 0; t < 8; ++t) acc[t] = (f4_t){0.f, 0.f, 0.f, 0.f};
    #pragma unroll
    for (int ks = 0; ks < 8; ++ks) {
        h4_t af = *(const h4_t*)(&Alds[w][c * 132 + ks * 16 + 4 * g]);
        #pragma unroll
        for (int t = 0; t < 8; ++t) {
            h4_t bf = *(const h4_t*)(&Blds[((ks * 8 + t) * 64 + l) * 4]);
            acc[t] = __builtin_amdgcn_mfma_f32_16x16x16f16(af, bf, acc[t], 0, 0, 0);
        }
    }

    // epilogue: ft (fp16) stores; a1/a2 via 16-lane butterfly on fp32 acc
    #pragma unroll
    for (int t = 0; t < 8; ++t) {
        #pragma unroll
        for (int r = 0; r < 4; ++r) {
            int v = v0 + 4 * g + r;
            if (v < n) ft[(size_t)v * FDIM + t * 16 + c] = __float2half(acc[t][r]);
        }
    }
    float al0[4], al1v[4], ar0[4], ar1v[4];
    #pragma unroll
    for (int h = 0; h < 4; ++h) {
        al0[h] = al[h * 32 + c]; al1v[h] = al[h * 32 + 16 + c];
        ar0[h] = ar[h * 32 + c]; ar1v[h] = ar[h * 32 + 16 + c];
    }
    #pragma unroll
    for (int r = 0; r < 4; ++r) {
        int v = v0 + 4 * g + r;
        #pragma unroll
        for (int h = 0; h < 4; ++h) {
            float p1 = acc[2 * h][r] * al0[h] + acc[2 * h + 1][r] * al1v[h];
            float p2 = acc[2 * h][r] * ar0[h] + acc[2 * h + 1][r] * ar1v[h];
            #pragma unroll
            for (int off = 1; off < 16; off <<= 1) {
                p1 += __shfl_xor(p1, off);
                p2 += __shfl_xor(p2, off);
            }
            if (c == h && v < n) {
                a1[v * 4 + h] = p1;
                a2[v * 4 + h] = p2;
            }
        }
    }
}

// ---------------- aggregate #2: wave-per-node, no-max softmax, post-divide ----------------
__global__ void k_agg2(const int* __restrict__ offs, const int* __restrict__ csr,
                       const __half* __restrict__ ft, const float* __restrict__ a1,
                       const float* __restrict__ a2, __half* __restrict__ out, int n) {
    __shared__ float wlds[4][64 * 4];
    int tid = threadIdx.x, lane = tid & 63, w = tid >> 6;
    int v = blockIdx.x * 4 + w;
    if (v >= n) return;
    int beg = offs[v], end = offs[v + 1];
    int deg = end - beg;
    float4 a2v = *(const float4*)(a2 + v * 4);
    int h = lane >> 4;
    int f = 2 * lane;
    float2 acc = make_float2(0.f, 0.f);
    float4 dsum = make_float4(0.f, 0.f, 0.f, 0.f);
    float* wbuf = wlds[w];
    for (int base = 0; base < deg; base += 64) {
        int m = min(64, deg - base);
        int u = 0;
        float4 wgt = make_float4(0.f, 0.f, 0.f, 0.f);
        if (lane < m) {
            u = csr[beg + base + lane];
            float4 a1u = *(const float4*)(a1 + u * 4);
            wgt.x = __expf(lrelu(a1u.x + a2v.x));
            wgt.y = __expf(lrelu(a1u.y + a2v.y));
            wgt.z = __expf(lrelu(a1u.z + a2v.z));
            wgt.w = __expf(lrelu(a1u.w + a2v.w));
        }
        dsum.x += wgt.x; dsum.y += wgt.y; dsum.z += wgt.z; dsum.w += wgt.w;
        *(float4*)(wbuf + lane * 4) = wgt;
        int j = 0;
        for (; j + 4 <= m; j += 4) {
            int s0 = __builtin_amdgcn_readlane(u, j);
            int s1 = __builtin_amdgcn_readlane(u, j + 1);
            int s2 = __builtin_amdgcn_readlane(u, j + 2);
            int s3 = __builtin_amdgcn_readlane(u, j + 3);
            float w0 = wbuf[(j + 0) * 4 + h];
            float w1 = wbuf[(j + 1) * 4 + h];
            float w2 = wbuf[(j + 2) * 4 + h];
            float w3 = wbuf[(j + 3) * 4 + h];
            float2 g0 = __half22float2(*(const __half2*)(ft + (size_t)s0 * FDIM + f));
            float2 g1 = __half22float2(*(const __half2*)(ft + (size_t)s1 * FDIM + f));
            float2 g2 = __half22float2(*(const __half2*)(ft + (size_t)s2 * FDIM + f));
            float2 g3 = __half22float2(*(const __half2*)(ft + (size_t)s3 * FDIM + f));
            acc.x = fmaf(w0, g0.x, acc.x); acc.y = fmaf(w0, g0.y, acc.y);
            acc.x = fmaf(w1, g1.x, acc.x); acc.y = fmaf(w1, g1.y, acc.y);
            acc.x = fmaf(w2, g2.x, acc.x); acc.y = fmaf(w2, g2.y, acc.y);
            acc.x = fmaf(w3, g3.x, acc.x); acc.y = fmaf(w3, g3.y, acc.y);
        }
        for (; j < m; ++j) {
            int s0 = __builtin_amdgcn_readlane(u, j);
            float w0 = wbuf[j * 4 + h];
            float2 g0 = __half22float2(*(const __half2*)(ft + (size_t)s0 * FDIM + f));
            acc.x = fmaf(w0, g0.x, acc.x); acc.y = fmaf(w0, g0.y, acc.y);
        }
    }
    #pragma unroll
    for (int off = 1; off < 64; off <<= 1) {
        dsum.x += __shfl_xor(dsum.x, off);
        dsum.y += __shfl_xor(dsum.y, off);
        dsum.z += __shfl_xor(dsum.z, off);
        dsum.w += __shfl_xor(dsum.w, off);
    }
    float dh = (h < 2) ? (h == 0 ? dsum.x : dsum.y) : (h == 2 ? dsum.z : dsum.w);
    float r = 1.0f / dh;
    *(__half2*)(out + (size_t)v * FDIM + f) =
        __floats2half2_rn(fmaxf(acc.x * r, 0.f), fmaxf(acc.y * r, 0.f));
}

// ---------------- per-graph mean pooling (run-length + atomics) ----------------
__global__ void k_pool(const __half* __restrict__ hbuf, const int* __restrict__ gid,
                       float* __restrict__ gsum, int* __restrict__ gcnt, int n) {
    const int STRIP = 32;
    int wv = (blockIdx.x * blockDim.x + threadIdx.x) >> 6;
    int lane = threadIdx.x & 63;
    int beg = wv * STRIP;
    if (beg >= n) return;
    int end = min(beg + STRIP, n);
    int f = 2 * lane;
    float2 acc = make_float2(0.f, 0.f);
    int cur = gid[beg];
    int cnt = 0;
    for (int i = beg; i < end; ++i) {
        int g = gid[i];
        if (g != cur) {
            atomicAdd(&gsum[cur * FDIM + f], acc.x);
            atomicAdd(&gsum[cur * FDIM + f + 1], acc.y);
            if (lane == 0) atomicAdd(&gcnt[cur], cnt);
            acc = make_float2(0.f, 0.f); cnt = 0; cur = g;
        }
        float2 x = __half22float2(*(const __half2*)(hbuf + (size_t)i * FDIM + f));
        acc.x += x.x; acc.y += x.y; cnt++;
    }
    atomicAdd(&gsum[cur * FDIM + f], acc.x);
    atomicAdd(&gsum[cur * FDIM + f + 1], acc.y);
    if (lane == 0) atomicAdd(&gcnt[cur], cnt);
}

// ---------------- classifier ----------------
__global__ void k_classify(const float* __restrict__ gsum, const int* __restrict__ gcnt,
                           const float* __restrict__ Wc, const float* __restrict__ bc,
                           float* __restrict__ out) {
    int idx = blockIdx.x * blockDim.x + threadIdx.x;
    if (idx >= NGRAPH * NCLASS) return;
    int g = idx / NCLASS, c = idx % NCLASS;
    float rc = 1.0f / fmaxf((float)gcnt[g], 1.0f);
    float s = bc[c];
    for (int k = 0; k < FDIM; ++k)
        s += gsum[g * FDIM + k] * rc * Wc[k * NCLASS + c];
    out[idx] = 1.0f / (1.0f + __expf(-s));
}

extern "C" void kernel_launch(void* const* d_in, const int* in_sizes, int n_in,
                              void* d_out, int out_size, void* d_ws, size_t ws_size,
                              hipStream_t stream) {
    const int*   src = (const int*)d_in[0];
    const int*   dst = (const int*)d_in[1];
    const int*   gid = (const int*)d_in[2];
    const float* W1  = (const float*)d_in[3];
    const float* al1 = (const float*)d_in[4];
    const float* ar1 = (const float*)d_in[5];
    const float* W2  = (const float*)d_in[6];
    const float* al2 = (const float*)d_in[7];
    const float* ar2 = (const float*)d_in[8];
    const float* Wc  = (const float*)d_in[9];
    const float* bc  = (const float*)d_in[10];
    float* out = (float*)d_out;
    const int E = in_sizes[0];
    const int N = in_sizes[2];

    char* ws = (char*)d_ws;
    size_t off = 0;
    auto alloc = [&](size_t bytes) -> void* {
        void* p = ws + off;
        off = (off + bytes + 255) & ~(size_t)255;
        return p;
    };
    int*    deg    = (int*)alloc((size_t)N * 4);
    int*    offs   = (int*)alloc((size_t)(N + 1) * 4);
    int*    cursor = (int*)alloc((size_t)N * 4);
    int*    csr    = (int*)alloc((size_t)E * 4);
    int*    bsum   = (int*)alloc((size_t)((N + 1023) / 1024) * 4);
    float*  h4t    = (float*)alloc((size_t)N * 4 * 4);
    float*  a1     = (float*)alloc((size_t)N * HEADS * 4);
    float*  a2     = (float*)alloc((size_t)N * HEADS * 4);
    float*  Sbuf   = (float*)alloc((size_t)N * 16 * 4);
    __half* ft16   = (__half*)alloc((size_t)N * FDIM * 2);
    __half* hbuf   = (__half*)alloc((size_t)N * FDIM * 2);
    __half* Wfrag  = (__half*)alloc((size_t)FDIM * FDIM * 2);
    float*  gsum   = (float*)alloc((size_t)NGRAPH * FDIM * 4);
    int*    gcnt   = (int*)alloc((size_t)NGRAPH * 4);

    (void)hipMemsetAsync(deg, 0, (size_t)N * 4, stream);

    int eb = (E + 255) / 256;
    int nb = (N + 1023) / 1024;
    k_hist<<<eb, 256, 0, stream>>>(dst, deg, E);
    k_bsum<<<nb, 256, 0, stream>>>(deg, bsum, N);
    k_bscan<<<1, 64, 0, stream>>>(bsum, nb, offs, N, E);
    k_offs<<<nb, 256, 0, stream>>>(deg, bsum, offs, cursor, gsum, gcnt, N);
    k_scatter<<<eb, 256, 0, stream>>>(src, dst, offs, cursor, csr, E);

    k_atts1<<<(N + 255) / 256, 256, 0, stream>>>(deg, W1, al1, ar1, h4t, a1, a2, N);
    k_agg1<<<(N + 15) / 16, 256, 0, stream>>>(offs, csr, h4t, a1, a2, Sbuf, N);
    k_wfrag<<<16, 256, 0, stream>>>(W2, Wfrag);
    k_layer2<<<(N + 63) / 64, 256, 0, stream>>>(Sbuf, W1, Wfrag, al2, ar2, ft16, a1, a2, N);
    k_agg2<<<(N + 3) / 4, 256, 0, stream>>>(offs, csr, ft16, a1, a2, hbuf, N);

    int pb = (((N + 31) / 32) + 3) / 4;
    k_pool<<<pb, 256, 0, stream>>>(hbuf, gid, gsum, gcnt, N);
    k_classify<<<(NGRAPH * NCLASS + 255) / 256, 256, 0, stream>>>(gsum, gcnt, Wc, bc, out);
}

// Round 6
// 194.537 us; speedup vs baseline: 2.1531x; 1.0013x over previous
//
#include <hip/hip_runtime.h>
#include <hip/hip_fp16.h>
#include <math.h>

#define HEADS 4
#define HDIM 32
#define FDIM 128   // HEADS*HDIM
#define NGRAPH 128
#define NCLASS 10

typedef _Float16 h4_t __attribute__((ext_vector_type(4)));
typedef float f4_t __attribute__((ext_vector_type(4)));

__device__ __forceinline__ float lrelu(float x) { return fmaxf(x, 0.2f * x); }

// ---------------- zero deg (custom: runtime fillBuffer is ~43us in-graph) ----------------
__global__ void k_zero(int* __restrict__ deg, int n4) {
    int i = blockIdx.x * blockDim.x + threadIdx.x;
    if (i < n4) ((int4*)deg)[i] = make_int4(0, 0, 0, 0);
}

// ---------------- histogram of dst (in-degree) ----------------
__global__ void k_hist(const int* __restrict__ dst, int* __restrict__ deg, int E) {
    int i = blockIdx.x * blockDim.x + threadIdx.x;
    if (i < E) atomicAdd(&deg[dst[i]], 1);
}

// ---------------- scan step 1: per-block (1024 elems) sums ----------------
__global__ void k_bsum(const int* __restrict__ deg, int* __restrict__ bsum, int n) {
    int tid = threadIdx.x, lane = tid & 63, w = tid >> 6;
    int base = blockIdx.x * 1024 + tid * 4;
    int t = 0;
    #pragma unroll
    for (int k = 0; k < 4; ++k) {
        int i = base + k;
        if (i < n) t += deg[i];
    }
    #pragma unroll
    for (int off = 1; off < 64; off <<= 1) t += __shfl_xor(t, off);
    __shared__ int ws[4];
    if (lane == 0) ws[w] = t;
    __syncthreads();
    if (tid == 0) bsum[blockIdx.x] = ws[0] + ws[1] + ws[2] + ws[3];
}

// ---------------- scan step 2: exclusive scan of block sums (1 wave) ----------------
__global__ void k_bscan(int* __restrict__ bsum, int nb, int* __restrict__ offs,
                        int n, int E) {
    int lane = threadIdx.x;
    int carry = 0;
    for (int base = 0; base < nb; base += 64) {
        int i = base + lane;
        int v = (i < nb) ? bsum[i] : 0;
        int p = v;
        #pragma unroll
        for (int off = 1; off < 64; off <<= 1) {
            int y = __shfl_up(p, off);
            if (lane >= off) p += y;
        }
        if (i < nb) bsum[i] = carry + p - v;   // exclusive
        carry += __shfl(p, 63);
    }
    if (lane == 0) offs[n] = E;
}

// ---------------- scan step 3: per-block exclusive offsets (+zero cursor/gsum/gcnt) ----------------
__global__ void k_offs(const int* __restrict__ deg, const int* __restrict__ boff,
                       int* __restrict__ offs, int* __restrict__ cursor,
                       float* __restrict__ gsum, int* __restrict__ gcnt, int n) {
    int tid = threadIdx.x, lane = tid & 63, w = tid >> 6;
    int gtid = blockIdx.x * 256 + tid;
    if (gtid < NGRAPH * FDIM / 4) ((float4*)gsum)[gtid] = make_float4(0.f, 0.f, 0.f, 0.f);
    if (gtid < NGRAPH) gcnt[gtid] = 0;
    int base = blockIdx.x * 1024 + tid * 4;
    int v[4]; int t = 0;
    #pragma unroll
    for (int k = 0; k < 4; ++k) {
        int i = base + k;
        v[k] = (i < n) ? deg[i] : 0;
        if (i < n) cursor[i] = 0;
        t += v[k];
    }
    int incl = t;
    #pragma unroll
    for (int off = 1; off < 64; off <<= 1) {
        int y = __shfl_up(incl, off);
        if (lane >= off) incl += y;
    }
    int lpre = incl - t;
    __shared__ int ws[4];
    if (lane == 63) ws[w] = incl;
    __syncthreads();
    int wpre = 0;
    #pragma unroll
    for (int j = 0; j < 4; ++j) if (j < w) wpre += ws[j];
    int g = boff[blockIdx.x] + wpre + lpre;
    #pragma unroll
    for (int k = 0; k < 4; ++k) {
        int i = base + k;
        if (i < n) offs[i] = g;
        g += v[k];
    }
}

// ---------------- CSR scatter (store src per slot) ----------------
__global__ void k_scatter(const int* __restrict__ src, const int* __restrict__ dst,
                          const int* __restrict__ offs, int* __restrict__ cursor,
                          int* __restrict__ csr_src, int E) {
    int i = blockIdx.x * blockDim.x + threadIdx.x;
    if (i < E) {
        int d = dst[i];
        int p = atomicAdd(&cursor[d], 1);
        csr_src[offs[d] + p] = src[i];
    }
}

// ---------------- layer-1 node features + attention coefficients ----------------
__global__ void k_atts1(const int* __restrict__ deg, const float* __restrict__ W1,
                        const float* __restrict__ al, const float* __restrict__ ar,
                        float* __restrict__ h4t, float* __restrict__ a1,
                        float* __restrict__ a2, int n) {
    __shared__ float wla[16], wlr[16];   // [k*4 + h]
    int tid = threadIdx.x;
    if (tid < 32) {
        int k = (tid & 15) >> 2, h = tid & 3;
        const float* av = (tid < 16) ? al : ar;
        float s = 0.f;
        #pragma unroll
        for (int d = 0; d < 32; ++d) s += W1[k * FDIM + h * HDIM + d] * av[h * HDIM + d];
        if (tid < 16) wla[k * 4 + h] = s; else wlr[k * 4 + h] = s;
    }
    __syncthreads();
    int v = blockIdx.x * blockDim.x + tid;
    if (v >= n) return;
    float d = (float)deg[v];
    float4 hv = make_float4(d, (d - 3.0f > 0.0f) ? 1.0f : 0.0f, 3.0f / d,
                            (d - 4.0f > 0.0f) ? 1.0f : 0.0f);
    *(float4*)(h4t + v * 4) = hv;
    float4 o1, o2;
    #pragma unroll
    for (int h = 0; h < 4; ++h) {
        float s1 = hv.x * wla[0 + h] + hv.y * wla[4 + h] + hv.z * wla[8 + h] + hv.w * wla[12 + h];
        float s2 = hv.x * wlr[0 + h] + hv.y * wlr[4 + h] + hv.z * wlr[8 + h] + hv.w * wlr[12 + h];
        if (h == 0) { o1.x = s1; o2.x = s2; } else if (h == 1) { o1.y = s1; o2.y = s2; }
        else if (h == 2) { o1.z = s1; o2.z = s2; } else { o1.w = s1; o2.w = s2; }
    }
    *(float4*)(a1 + v * 4) = o1;
    *(float4*)(a2 + v * 4) = o2;
}

// ---------------- aggregate #1 in 4-dim feature space ----------------
__global__ void k_agg1(const int* __restrict__ offs, const int* __restrict__ csr,
                       const float* __restrict__ h4t, const float* __restrict__ a1,
                       const float* __restrict__ a2, float* __restrict__ S, int n) {
    int tid = threadIdx.x, lane = tid & 63, w = tid >> 6;
    int g = lane >> 4, e = lane & 15;
    int v = (blockIdx.x * 4 + w) * 4 + g;
    bool vok = v < n;
    int beg = 0, end = 0;
    if (vok) { beg = offs[v]; end = offs[v + 1]; }
    int deg = end - beg;
    float4 a2v = vok ? *(const float4*)(a2 + v * 4) : make_float4(0, 0, 0, 0);
    float P[4][4]; float D[4];
    #pragma unroll
    for (int h = 0; h < 4; ++h) { D[h] = 0.f;
        #pragma unroll
        for (int d = 0; d < 4; ++d) P[h][d] = 0.f; }
    for (int base = 0; base < deg; base += 16) {
        if (base + e < deg) {
            int u = csr[beg + base + e];
            float4 a1u = *(const float4*)(a1 + u * 4);
            float4 f4  = *(const float4*)(h4t + u * 4);
            float wgt[4];
            wgt[0] = __expf(lrelu(a1u.x + a2v.x));
            wgt[1] = __expf(lrelu(a1u.y + a2v.y));
            wgt[2] = __expf(lrelu(a1u.z + a2v.z));
            wgt[3] = __expf(lrelu(a1u.w + a2v.w));
            #pragma unroll
            for (int h = 0; h < 4; ++h) {
                D[h] += wgt[h];
                P[h][0] = fmaf(wgt[h], f4.x, P[h][0]);
                P[h][1] = fmaf(wgt[h], f4.y, P[h][1]);
                P[h][2] = fmaf(wgt[h], f4.z, P[h][2]);
                P[h][3] = fmaf(wgt[h], f4.w, P[h][3]);
            }
        }
    }
    #pragma unroll
    for (int off = 1; off < 16; off <<= 1) {
        #pragma unroll
        for (int h = 0; h < 4; ++h) {
            D[h] += __shfl_xor(D[h], off);
            #pragma unroll
            for (int d = 0; d < 4; ++d) P[h][d] += __shfl_xor(P[h][d], off);
        }
    }
    if (vok && e == 0) {
        #pragma unroll
        for (int h = 0; h < 4; ++h) {
            float r = 1.0f / D[h];
            *(float4*)(S + v * 16 + h * 4) =
                make_float4(P[h][0] * r, P[h][1] * r, P[h][2] * r, P[h][3] * r);
        }
    }
}

// ---------------- W2 -> fp16 fragments in MFMA lane order ----------------
__global__ void k_wfrag(const float* __restrict__ W2, __half* __restrict__ Wfrag) {
    int gid = blockIdx.x * 256 + threadIdx.x;   // 4096 threads
    int fid = gid >> 6, l = gid & 63;
    int ks = fid >> 3, t = fid & 7;
    int k0 = ks * 16 + 4 * (l >> 4);
    int n0 = t * 16 + (l & 15);
    __half2 lo = __floats2half2_rn(W2[(k0 + 0) * FDIM + n0], W2[(k0 + 1) * FDIM + n0]);
    __half2 hi = __floats2half2_rn(W2[(k0 + 2) * FDIM + n0], W2[(k0 + 3) * FDIM + n0]);
    size_t base = ((size_t)fid * 64 + l) * 4;
    *(__half2*)(Wfrag + base)     = lo;
    *(__half2*)(Wfrag + base + 2) = hi;
}

// ---------------- layer 2 via MFMA: ft = relu(S@W1) @ W2, + attn coeffs ----------------
__global__ __launch_bounds__(256) void k_layer2(const float* __restrict__ S,
        const float* __restrict__ W1, const __half* __restrict__ Wfrag,
        const float* __restrict__ al, const float* __restrict__ ar,
        __half* __restrict__ ft, float* __restrict__ a1, float* __restrict__ a2, int n) {
    __shared__ __half Blds[64 * 64 * 4];        // 32 KB: 64 frags x 64 lanes x 4 halves
    __shared__ __half Alds[4][16 * 132];        // per-wave 16 nodes x 128 k, pitch 132
    int tid = threadIdx.x, l = tid & 63, w = tid >> 6;
    int c = l & 15, g = l >> 4;

    #pragma unroll
    for (int i = 0; i < 8; ++i)
        ((float4*)Blds)[i * 256 + tid] = ((const float4*)Wfrag)[i * 256 + tid];

    int v0 = (blockIdx.x * 4 + w) * 16;
    float2 w1c[4];
    #pragma unroll
    for (int d = 0; d < 4; ++d) w1c[d] = *(const float2*)(W1 + d * FDIM + 2 * l);
    for (int jj = 0; jj < 16; ++jj) {
        int v = min(v0 + jj, n - 1);
        float4 s = *(const float4*)(S + v * 16 + g * 4);
        float t0 = s.x * w1c[0].x + s.y * w1c[1].x + s.z * w1c[2].x + s.w * w1c[3].x;
        float t1 = s.x * w1c[0].y + s.y * w1c[1].y + s.z * w1c[2].y + s.w * w1c[3].y;
        *(__half2*)(&Alds[w][jj * 132 + 2 * l]) = __floats2half2_rn(fmaxf(t0, 0.f), fmaxf(t1, 0.f));
    }
    __syncthreads();

    f4_t acc[8];
    #pragma unroll
    for (int t = 0; t < 8; ++t) acc[t] = (f4_t){0.f, 0.f, 0.f, 0.f};
    #pragma unroll
    for (int ks = 0; ks < 8; ++ks) {
        h4_t af = *(const h4_t*)(&Alds[w][c * 132 + ks * 16 + 4 * g]);
        #pragma unroll
        for (int t = 0; t < 8; ++t) {
            h4_t bf = *(const h4_t*)(&Blds[((ks * 8 + t) * 64 + l) * 4]);
            acc[t] = __builtin_amdgcn_mfma_f32_16x16x16f16(af, bf, acc[t], 0, 0, 0);
        }
    }

    #pragma unroll
    for (int t = 0; t < 8; ++t) {
        #pragma unroll
        for (int r = 0; r < 4; ++r) {
            int v = v0 + 4 * g + r;
            if (v < n) ft[(size_t)v * FDIM + t * 16 + c] = __float2half(acc[t][r]);
        }
    }
    float al0[4], al1v[4], ar0[4], ar1v[4];
    #pragma unroll
    for (int h = 0; h < 4; ++h) {
        al0[h] = al[h * 32 + c]; al1v[h] = al[h * 32 + 16 + c];
        ar0[h] = ar[h * 32 + c]; ar1v[h] = ar[h * 32 + 16 + c];
    }
    #pragma unroll
    for (int r = 0; r < 4; ++r) {
        int v = v0 + 4 * g + r;
        #pragma unroll
        for (int h = 0; h < 4; ++h) {
            float p1 = acc[2 * h][r] * al0[h] + acc[2 * h + 1][r] * al1v[h];
            float p2 = acc[2 * h][r] * ar0[h] + acc[2 * h + 1][r] * ar1v[h];
            #pragma unroll
            for (int off = 1; off < 16; off <<= 1) {
                p1 += __shfl_xor(p1, off);
                p2 += __shfl_xor(p2, off);
            }
            if (c == h && v < n) {
                a1[v * 4 + h] = p1;
                a2[v * 4 + h] = p2;
            }
        }
    }
}

// ---------------- aggregate #2: wave-per-node, no-max softmax, post-divide ----------------
__global__ void k_agg2(const int* __restrict__ offs, const int* __restrict__ csr,
                       const __half* __restrict__ ft, const float* __restrict__ a1,
                       const float* __restrict__ a2, __half* __restrict__ out, int n) {
    __shared__ float wlds[4][64 * 4];
    int tid = threadIdx.x, lane = tid & 63, w = tid >> 6;
    int v = blockIdx.x * 4 + w;
    if (v >= n) return;
    int beg = offs[v], end = offs[v + 1];
    int deg = end - beg;
    float4 a2v = *(const float4*)(a2 + v * 4);
    int h = lane >> 4;
    int f = 2 * lane;
    float2 acc = make_float2(0.f, 0.f);
    float4 dsum = make_float4(0.f, 0.f, 0.f, 0.f);
    float* wbuf = wlds[w];
    for (int base = 0; base < deg; base += 64) {
        int m = min(64, deg - base);
        int u = 0;
        float4 wgt = make_float4(0.f, 0.f, 0.f, 0.f);
        if (lane < m) {
            u = csr[beg + base + lane];
            float4 a1u = *(const float4*)(a1 + u * 4);
            wgt.x = __expf(lrelu(a1u.x + a2v.x));
            wgt.y = __expf(lrelu(a1u.y + a2v.y));
            wgt.z = __expf(lrelu(a1u.z + a2v.z));
            wgt.w = __expf(lrelu(a1u.w + a2v.w));
        }
        dsum.x += wgt.x; dsum.y += wgt.y; dsum.z += wgt.z; dsum.w += wgt.w;
        *(float4*)(wbuf + lane * 4) = wgt;
        int j = 0;
        for (; j + 4 <= m; j += 4) {
            int s0 = __builtin_amdgcn_readlane(u, j);
            int s1 = __builtin_amdgcn_readlane(u, j + 1);
            int s2 = __builtin_amdgcn_readlane(u, j + 2);
            int s3 = __builtin_amdgcn_readlane(u, j + 3);
            float w0 = wbuf[(j + 0) * 4 + h];
            float w1 = wbuf[(j + 1) * 4 + h];
            float w2 = wbuf[(j + 2) * 4 + h];
            float w3 = wbuf[(j + 3) * 4 + h];
            float2 g0 = __half22float2(*(const __half2*)(ft + (size_t)s0 * FDIM + f));
            float2 g1 = __half22float2(*(const __half2*)(ft + (size_t)s1 * FDIM + f));
            float2 g2 = __half22float2(*(const __half2*)(ft + (size_t)s2 * FDIM + f));
            float2 g3 = __half22float2(*(const __half2*)(ft + (size_t)s3 * FDIM + f));
            acc.x = fmaf(w0, g0.x, acc.x); acc.y = fmaf(w0, g0.y, acc.y);
            acc.x = fmaf(w1, g1.x, acc.x); acc.y = fmaf(w1, g1.y, acc.y);
            acc.x = fmaf(w2, g2.x, acc.x); acc.y = fmaf(w2, g2.y, acc.y);
            acc.x = fmaf(w3, g3.x, acc.x); acc.y = fmaf(w3, g3.y, acc.y);
        }
        for (; j < m; ++j) {
            int s0 = __builtin_amdgcn_readlane(u, j);
            float w0 = wbuf[j * 4 + h];
            float2 g0 = __half22float2(*(const __half2*)(ft + (size_t)s0 * FDIM + f));
            acc.x = fmaf(w0, g0.x, acc.x); acc.y = fmaf(w0, g0.y, acc.y);
        }
    }
    #pragma unroll
    for (int off = 1; off < 64; off <<= 1) {
        dsum.x += __shfl_xor(dsum.x, off);
        dsum.y += __shfl_xor(dsum.y, off);
        dsum.z += __shfl_xor(dsum.z, off);
        dsum.w += __shfl_xor(dsum.w, off);
    }
    float dh = (h < 2) ? (h == 0 ? dsum.x : dsum.y) : (h == 2 ? dsum.z : dsum.w);
    float r = 1.0f / dh;
    *(__half2*)(out + (size_t)v * FDIM + f) =
        __floats2half2_rn(fmaxf(acc.x * r, 0.f), fmaxf(acc.y * r, 0.f));
}

// ---------------- per-graph mean pooling (run-length + atomics) ----------------
__global__ void k_pool(const __half* __restrict__ hbuf, const int* __restrict__ gid,
                       float* __restrict__ gsum, int* __restrict__ gcnt, int n) {
    const int STRIP = 32;
    int wv = (blockIdx.x * blockDim.x + threadIdx.x) >> 6;
    int lane = threadIdx.x & 63;
    int beg = wv * STRIP;
    if (beg >= n) return;
    int end = min(beg + STRIP, n);
    int f = 2 * lane;
    float2 acc = make_float2(0.f, 0.f);
    int cur = gid[beg];
    int cnt = 0;
    for (int i = beg; i < end; ++i) {
        int g = gid[i];
        if (g != cur) {
            atomicAdd(&gsum[cur * FDIM + f], acc.x);
            atomicAdd(&gsum[cur * FDIM + f + 1], acc.y);
            if (lane == 0) atomicAdd(&gcnt[cur], cnt);
            acc = make_float2(0.f, 0.f); cnt = 0; cur = g;
        }
        float2 x = __half22float2(*(const __half2*)(hbuf + (size_t)i * FDIM + f));
        acc.x += x.x; acc.y += x.y; cnt++;
    }
    atomicAdd(&gsum[cur * FDIM + f], acc.x);
    atomicAdd(&gsum[cur * FDIM + f + 1], acc.y);
    if (lane == 0) atomicAdd(&gcnt[cur], cnt);
}

// ---------------- classifier ----------------
__global__ void k_classify(const float* __restrict__ gsum, const int* __restrict__ gcnt,
                           const float* __restrict__ Wc, const float* __restrict__ bc,
                           float* __restrict__ out) {
    int idx = blockIdx.x * blockDim.x + threadIdx.x;
    if (idx >= NGRAPH * NCLASS) return;
    int g = idx / NCLASS, c = idx % NCLASS;
    float rc = 1.0f / fmaxf((float)gcnt[g], 1.0f);
    float s = bc[c];
    for (int k = 0; k < FDIM; ++k)
        s += gsum[g * FDIM + k] * rc * Wc[k * NCLASS + c];
    out[idx] = 1.0f / (1.0f + __expf(-s));
}

extern "C" void kernel_launch(void* const* d_in, const int* in_sizes, int n_in,
                              void* d_out, int out_size, void* d_ws, size_t ws_size,
                              hipStream_t stream) {
    const int*   src = (const int*)d_in[0];
    const int*   dst = (const int*)d_in[1];
    const int*   gid = (const int*)d_in[2];
    const float* W1  = (const float*)d_in[3];
    const float* al1 = (const float*)d_in[4];
    const float* ar1 = (const float*)d_in[5];
    const float* W2  = (const float*)d_in[6];
    const float* al2 = (const float*)d_in[7];
    const float* ar2 = (const float*)d_in[8];
    const float* Wc  = (const float*)d_in[9];
    const float* bc  = (const float*)d_in[10];
    float* out = (float*)d_out;
    const int E = in_sizes[0];
    const int N = in_sizes[2];

    char* ws = (char*)d_ws;
    size_t off = 0;
    auto alloc = [&](size_t bytes) -> void* {
        void* p = ws + off;
        off = (off + bytes + 255) & ~(size_t)255;
        return p;
    };
    int*    deg    = (int*)alloc((size_t)N * 4);
    int*    offs   = (int*)alloc((size_t)(N + 1) * 4);
    int*    cursor = (int*)alloc((size_t)N * 4);
    int*    csr    = (int*)alloc((size_t)E * 4);
    int*    bsum   = (int*)alloc((size_t)((N + 1023) / 1024) * 4);
    float*  h4t    = (float*)alloc((size_t)N * 4 * 4);
    float*  a1     = (float*)alloc((size_t)N * HEADS * 4);
    float*  a2     = (float*)alloc((size_t)N * HEADS * 4);
    float*  Sbuf   = (float*)alloc((size_t)N * 16 * 4);
    __half* ft16   = (__half*)alloc((size_t)N * FDIM * 2);
    __half* hbuf   = (__half*)alloc((size_t)N * FDIM * 2);
    __half* Wfrag  = (__half*)alloc((size_t)FDIM * FDIM * 2);
    float*  gsum   = (float*)alloc((size_t)NGRAPH * FDIM * 4);
    int*    gcnt   = (int*)alloc((size_t)NGRAPH * 4);

    int eb = (E + 255) / 256;
    int nb = (N + 1023) / 1024;
    int n4 = (N + 3) / 4;
    k_zero<<<(n4 + 255) / 256, 256, 0, stream>>>(deg, n4);
    k_hist<<<eb, 256, 0, stream>>>(dst, deg, E);
    k_bsum<<<nb, 256, 0, stream>>>(deg, bsum, N);
    k_bscan<<<1, 64, 0, stream>>>(bsum, nb, offs, N, E);
    k_offs<<<nb, 256, 0, stream>>>(deg, bsum, offs, cursor, gsum, gcnt, N);
    k_scatter<<<eb, 256, 0, stream>>>(src, dst, offs, cursor, csr, E);

    k_atts1<<<(N + 255) / 256, 256, 0, stream>>>(deg, W1, al1, ar1, h4t, a1, a2, N);
    k_agg1<<<(N + 15) / 16, 256, 0, stream>>>(offs, csr, h4t, a1, a2, Sbuf, N);
    k_wfrag<<<16, 256, 0, stream>>>(W2, Wfrag);
    k_layer2<<<(N + 63) / 64, 256, 0, stream>>>(Sbuf, W1, Wfrag, al2, ar2, ft16, a1, a2, N);
    k_agg2<<<(N + 3) / 4, 256, 0, stream>>>(offs, csr, ft16, a1, a2, hbuf, N);

    int pb = (((N + 31) / 32) + 3) / 4;
    k_pool<<<pb, 256, 0, stream>>>(hbuf, gid, gsum, gcnt, N);
    k_classify<<<(NGRAPH * NCLASS + 255) / 256, 256, 0, stream>>>(gsum, gcnt, Wc, bc, out);
}

// Round 7
// 155.139 us; speedup vs baseline: 2.6999x; 1.2540x over previous
//
#include <hip/hip_runtime.h>
#include <hip/hip_fp16.h>
#include <math.h>

#define HEADS 4
#define HDIM 32
#define FDIM 128   // HEADS*HDIM
#define NGRAPH 128
#define NCLASS 10

#define NBW 128            // nodes per bucket (bucket = dst >> 7)
#define NBP 512            // padded bucket count (>= ceil(50000/128)=391)
#define SLICE 4096         // edges per partition block

typedef _Float16 h4_t __attribute__((ext_vector_type(4)));
typedef float f4_t __attribute__((ext_vector_type(4)));

__device__ __forceinline__ float lrelu(float x) { return fmaxf(x, 0.2f * x); }

// ---------------- zero small bucket arrays ----------------
__global__ void k_zb(int* __restrict__ bcnt) {
    int i = threadIdx.x;
    bcnt[i] = 0; bcnt[i + 256] = 0;
}

// ---------------- bucket histogram (LDS-staged, few global atomics) ----------------
__global__ void k_bhist(const int* __restrict__ dst, int E, int* __restrict__ bcnt) {
    __shared__ int lcnt[NBP];
    int tid = threadIdx.x;
    for (int i = tid; i < NBP; i += 256) lcnt[i] = 0;
    __syncthreads();
    int beg = blockIdx.x * SLICE, end = min(E, beg + SLICE);
    for (int i = beg + tid; i < end; i += 256)
        atomicAdd(&lcnt[dst[i] >> 7], 1);
    __syncthreads();
    for (int i = tid; i < NBP; i += 256)
        if (lcnt[i]) atomicAdd(&bcnt[i], lcnt[i]);
}

// ---------------- exclusive scan of 512 bucket counts (1 block) ----------------
__global__ void k_bscan2(const int* __restrict__ bcnt, int* __restrict__ bbase,
                         int* __restrict__ bcur) {
    __shared__ int ws[4];
    int tid = threadIdx.x, lane = tid & 63, w = tid >> 6;
    int c0 = bcnt[2 * tid], c1 = bcnt[2 * tid + 1];
    int t = c0 + c1;
    int incl = t;
    #pragma unroll
    for (int off = 1; off < 64; off <<= 1) {
        int y = __shfl_up(incl, off);
        if (lane >= off) incl += y;
    }
    if (lane == 63) ws[w] = incl;
    __syncthreads();
    int wpre = 0;
    #pragma unroll
    for (int j = 0; j < 4; ++j) if (j < w) wpre += ws[j];
    int ex = wpre + (incl - t);
    bbase[2 * tid] = ex;          bcur[2 * tid] = ex;
    bbase[2 * tid + 1] = ex + c0; bcur[2 * tid + 1] = ex + c0;
}

// ---------------- partition edges into bucket-grouped part[] (coalesced writes) ----------------
__global__ __launch_bounds__(256) void k_part(const int* __restrict__ src,
        const int* __restrict__ dst, int E, int* __restrict__ bcur,
        int2* __restrict__ part) {
    __shared__ int lcnt[NBP];
    __shared__ int loff[NBP];
    __shared__ int lpos[NBP];
    __shared__ int2 staged[SLICE];
    __shared__ int tgt[SLICE];
    __shared__ int ws[4];
    int tid = threadIdx.x, lane = tid & 63, w = tid >> 6;
    int beg = blockIdx.x * SLICE, end = min(E, beg + SLICE);
    int m = end - beg;
    for (int i = tid; i < NBP; i += 256) lcnt[i] = 0;
    __syncthreads();
    for (int i = beg + tid; i < end; i += 256)
        atomicAdd(&lcnt[dst[i] >> 7], 1);
    __syncthreads();
    // exclusive scan of lcnt[512]: each thread owns entries 2t, 2t+1
    int c0 = lcnt[2 * tid], c1 = lcnt[2 * tid + 1];
    int t = c0 + c1;
    int incl = t;
    #pragma unroll
    for (int off = 1; off < 64; off <<= 1) {
        int y = __shfl_up(incl, off);
        if (lane >= off) incl += y;
    }
    if (lane == 63) ws[w] = incl;
    __syncthreads();
    int wpre = 0;
    #pragma unroll
    for (int j = 0; j < 4; ++j) if (j < w) wpre += ws[j];
    int ex = wpre + (incl - t);
    loff[2 * tid] = ex; loff[2 * tid + 1] = ex + c0;
    if (c0) lpos[2 * tid] = atomicAdd(&bcur[2 * tid], c0);
    if (c1) lpos[2 * tid + 1] = atomicAdd(&bcur[2 * tid + 1], c1);
    lcnt[2 * tid] = 0; lcnt[2 * tid + 1] = 0;
    __syncthreads();
    // insert into bucket-contiguous LDS staging
    for (int i = beg + tid; i < end; i += 256) {
        int s = src[i], d = dst[i];
        int b = d >> 7;
        int idx = atomicAdd(&lcnt[b], 1);
        int slot = loff[b] + idx;
        staged[slot] = make_int2(s, d);
        tgt[slot] = lpos[b] + idx;
    }
    __syncthreads();
    // copy out: consecutive threads -> consecutive targets within each run
    for (int i = tid; i < m; i += 256)
        part[tgt[i]] = staged[i];
}

// ---------------- per-bucket degree histogram (LDS only, coalesced deg write) ----------------
__global__ void k_deg(const int2* __restrict__ part, const int* __restrict__ bbase,
                      const int* __restrict__ bcnt, int* __restrict__ deg, int n) {
    __shared__ int lcnt[NBW];
    int b = blockIdx.x, tid = threadIdx.x;
    if (tid < NBW) lcnt[tid] = 0;
    __syncthreads();
    int beg = bbase[b], end = beg + bcnt[b];
    for (int i = beg + tid; i < end; i += 256)
        atomicAdd(&lcnt[part[i].y & (NBW - 1)], 1);
    __syncthreads();
    int v = b * NBW + tid;
    if (tid < NBW && v < n) deg[v] = lcnt[tid];
}

// ---------------- scan step 1: per-block (1024 elems) sums ----------------
__global__ void k_bsum(const int* __restrict__ deg, int* __restrict__ bsum, int n) {
    int tid = threadIdx.x, lane = tid & 63, w = tid >> 6;
    int base = blockIdx.x * 1024 + tid * 4;
    int t = 0;
    #pragma unroll
    for (int k = 0; k < 4; ++k) {
        int i = base + k;
        if (i < n) t += deg[i];
    }
    #pragma unroll
    for (int off = 1; off < 64; off <<= 1) t += __shfl_xor(t, off);
    __shared__ int ws[4];
    if (lane == 0) ws[w] = t;
    __syncthreads();
    if (tid == 0) bsum[blockIdx.x] = ws[0] + ws[1] + ws[2] + ws[3];
}

// ---------------- scan step 2: exclusive scan of block sums (1 wave) ----------------
__global__ void k_bscan(int* __restrict__ bsum, int nb, int* __restrict__ offs,
                        int n, int E) {
    int lane = threadIdx.x;
    int carry = 0;
    for (int base = 0; base < nb; base += 64) {
        int i = base + lane;
        int v = (i < nb) ? bsum[i] : 0;
        int p = v;
        #pragma unroll
        for (int off = 1; off < 64; off <<= 1) {
            int y = __shfl_up(p, off);
            if (lane >= off) p += y;
        }
        if (i < nb) bsum[i] = carry + p - v;   // exclusive
        carry += __shfl(p, 63);
    }
    if (lane == 0) offs[n] = E;
}

// ---------------- scan step 3: per-block exclusive offsets (+zero gsum/gcnt) ----------------
__global__ void k_offs(const int* __restrict__ deg, const int* __restrict__ boff,
                       int* __restrict__ offs, float* __restrict__ gsum,
                       int* __restrict__ gcnt, int n) {
    int tid = threadIdx.x, lane = tid & 63, w = tid >> 6;
    int gtid = blockIdx.x * 256 + tid;
    if (gtid < NGRAPH * FDIM / 4) ((float4*)gsum)[gtid] = make_float4(0.f, 0.f, 0.f, 0.f);
    if (gtid < NGRAPH) gcnt[gtid] = 0;
    int base = blockIdx.x * 1024 + tid * 4;
    int v[4]; int t = 0;
    #pragma unroll
    for (int k = 0; k < 4; ++k) {
        int i = base + k;
        v[k] = (i < n) ? deg[i] : 0;
        t += v[k];
    }
    int incl = t;
    #pragma unroll
    for (int off = 1; off < 64; off <<= 1) {
        int y = __shfl_up(incl, off);
        if (lane >= off) incl += y;
    }
    int lpre = incl - t;
    __shared__ int ws[4];
    if (lane == 63) ws[w] = incl;
    __syncthreads();
    int wpre = 0;
    #pragma unroll
    for (int j = 0; j < 4; ++j) if (j < w) wpre += ws[j];
    int g = boff[blockIdx.x] + wpre + lpre;
    #pragma unroll
    for (int k = 0; k < 4; ++k) {
        int i = base + k;
        if (i < n) offs[i] = g;
        g += v[k];
    }
}

// ---------------- per-bucket CSR scatter: LDS cursor, writes confined to 8KB window ----------------
__global__ void k_scatter2(const int2* __restrict__ part, const int* __restrict__ bbase,
                           const int* __restrict__ bcnt, const int* __restrict__ offs,
                           int* __restrict__ csr, int n) {
    __shared__ int lcur[NBW];
    int b = blockIdx.x, tid = threadIdx.x;
    if (tid < NBW) lcur[tid] = 0;
    __syncthreads();
    int beg = bbase[b], end = beg + bcnt[b];
    for (int i = beg + tid; i < end; i += 256) {
        int2 e = part[i];
        int d = e.y;
        int p = atomicAdd(&lcur[d & (NBW - 1)], 1);
        csr[offs[d] + p] = e.x;
    }
}

// ---------------- layer-1 node features + attention coefficients ----------------
__global__ void k_atts1(const int* __restrict__ deg, const float* __restrict__ W1,
                        const float* __restrict__ al, const float* __restrict__ ar,
                        float* __restrict__ h4t, float* __restrict__ a1,
                        float* __restrict__ a2, int n) {
    __shared__ float wla[16], wlr[16];   // [k*4 + h]
    int tid = threadIdx.x;
    if (tid < 32) {
        int k = (tid & 15) >> 2, h = tid & 3;
        const float* av = (tid < 16) ? al : ar;
        float s = 0.f;
        #pragma unroll
        for (int d = 0; d < 32; ++d) s += W1[k * FDIM + h * HDIM + d] * av[h * HDIM + d];
        if (tid < 16) wla[k * 4 + h] = s; else wlr[k * 4 + h] = s;
    }
    __syncthreads();
    int v = blockIdx.x * blockDim.x + tid;
    if (v >= n) return;
    float d = (float)deg[v];
    float4 hv = make_float4(d, (d - 3.0f > 0.0f) ? 1.0f : 0.0f, 3.0f / d,
                            (d - 4.0f > 0.0f) ? 1.0f : 0.0f);
    *(float4*)(h4t + v * 4) = hv;
    float4 o1, o2;
    #pragma unroll
    for (int h = 0; h < 4; ++h) {
        float s1 = hv.x * wla[0 + h] + hv.y * wla[4 + h] + hv.z * wla[8 + h] + hv.w * wla[12 + h];
        float s2 = hv.x * wlr[0 + h] + hv.y * wlr[4 + h] + hv.z * wlr[8 + h] + hv.w * wlr[12 + h];
        if (h == 0) { o1.x = s1; o2.x = s2; } else if (h == 1) { o1.y = s1; o2.y = s2; }
        else if (h == 2) { o1.z = s1; o2.z = s2; } else { o1.w = s1; o2.w = s2; }
    }
    *(float4*)(a1 + v * 4) = o1;
    *(float4*)(a2 + v * 4) = o2;
}

// ---------------- aggregate #1 in 4-dim feature space ----------------
__global__ void k_agg1(const int* __restrict__ offs, const int* __restrict__ csr,
                       const float* __restrict__ h4t, const float* __restrict__ a1,
                       const float* __restrict__ a2, float* __restrict__ S, int n) {
    int tid = threadIdx.x, lane = tid & 63, w = tid >> 6;
    int g = lane >> 4, e = lane & 15;
    int v = (blockIdx.x * 4 + w) * 4 + g;
    bool vok = v < n;
    int beg = 0, end = 0;
    if (vok) { beg = offs[v]; end = offs[v + 1]; }
    int deg = end - beg;
    float4 a2v = vok ? *(const float4*)(a2 + v * 4) : make_float4(0, 0, 0, 0);
    float P[4][4]; float D[4];
    #pragma unroll
    for (int h = 0; h < 4; ++h) { D[h] = 0.f;
        #pragma unroll
        for (int d = 0; d < 4; ++d) P[h][d] = 0.f; }
    for (int base = 0; base < deg; base += 16) {
        if (base + e < deg) {
            int u = csr[beg + base + e];
            float4 a1u = *(const float4*)(a1 + u * 4);
            float4 f4  = *(const float4*)(h4t + u * 4);
            float wgt[4];
            wgt[0] = __expf(lrelu(a1u.x + a2v.x));
            wgt[1] = __expf(lrelu(a1u.y + a2v.y));
            wgt[2] = __expf(lrelu(a1u.z + a2v.z));
            wgt[3] = __expf(lrelu(a1u.w + a2v.w));
            #pragma unroll
            for (int h = 0; h < 4; ++h) {
                D[h] += wgt[h];
                P[h][0] = fmaf(wgt[h], f4.x, P[h][0]);
                P[h][1] = fmaf(wgt[h], f4.y, P[h][1]);
                P[h][2] = fmaf(wgt[h], f4.z, P[h][2]);
                P[h][3] = fmaf(wgt[h], f4.w, P[h][3]);
            }
        }
    }
    #pragma unroll
    for (int off = 1; off < 16; off <<= 1) {
        #pragma unroll
        for (int h = 0; h < 4; ++h) {
            D[h] += __shfl_xor(D[h], off);
            #pragma unroll
            for (int d = 0; d < 4; ++d) P[h][d] += __shfl_xor(P[h][d], off);
        }
    }
    if (vok && e == 0) {
        #pragma unroll
        for (int h = 0; h < 4; ++h) {
            float r = 1.0f / D[h];
            *(float4*)(S + v * 16 + h * 4) =
                make_float4(P[h][0] * r, P[h][1] * r, P[h][2] * r, P[h][3] * r);
        }
    }
}

// ---------------- W2 -> fp16 fragments in MFMA lane order ----------------
__global__ void k_wfrag(const float* __restrict__ W2, __half* __restrict__ Wfrag) {
    int gid = blockIdx.x * 256 + threadIdx.x;   // 4096 threads
    int fid = gid >> 6, l = gid & 63;
    int ks = fid >> 3, t = fid & 7;
    int k0 = ks * 16 + 4 * (l >> 4);
    int n0 = t * 16 + (l & 15);
    __half2 lo = __floats2half2_rn(W2[(k0 + 0) * FDIM + n0], W2[(k0 + 1) * FDIM + n0]);
    __half2 hi = __floats2half2_rn(W2[(k0 + 2) * FDIM + n0], W2[(k0 + 3) * FDIM + n0]);
    size_t base = ((size_t)fid * 64 + l) * 4;
    *(__half2*)(Wfrag + base)     = lo;
    *(__half2*)(Wfrag + base + 2) = hi;
}

// ---------------- layer 2 via MFMA: ft = relu(S@W1) @ W2, + attn coeffs ----------------
__global__ __launch_bounds__(256) void k_layer2(const float* __restrict__ S,
        const float* __restrict__ W1, const __half* __restrict__ Wfrag,
        const float* __restrict__ al, const float* __restrict__ ar,
        __half* __restrict__ ft, float* __restrict__ a1, float* __restrict__ a2, int n) {
    __shared__ __half Blds[64 * 64 * 4];        // 32 KB
    __shared__ __half Alds[4][16 * 132];
    int tid = threadIdx.x, l = tid & 63, w = tid >> 6;
    int c = l & 15, g = l >> 4;

    #pragma unroll
    for (int i = 0; i < 8; ++i)
        ((float4*)Blds)[i * 256 + tid] = ((const float4*)Wfrag)[i * 256 + tid];

    int v0 = (blockIdx.x * 4 + w) * 16;
    float2 w1c[4];
    #pragma unroll
    for (int d = 0; d < 4; ++d) w1c[d] = *(const float2*)(W1 + d * FDIM + 2 * l);
    for (int jj = 0; jj < 16; ++jj) {
        int v = min(v0 + jj, n - 1);
        float4 s = *(const float4*)(S + v * 16 + g * 4);
        float t0 = s.x * w1c[0].x + s.y * w1c[1].x + s.z * w1c[2].x + s.w * w1c[3].x;
        float t1 = s.x * w1c[0].y + s.y * w1c[1].y + s.z * w1c[2].y + s.w * w1c[3].y;
        *(__half2*)(&Alds[w][jj * 132 + 2 * l]) = __floats2half2_rn(fmaxf(t0, 0.f), fmaxf(t1, 0.f));
    }
    __syncthreads();

    f4_t acc[8];
    #pragma unroll
    for (int t = 0; t < 8; ++t) acc[t] = (f4_t){0.f, 0.f, 0.f, 0.f};
    #pragma unroll
    for (int ks = 0; ks < 8; ++ks) {
        h4_t af = *(const h4_t*)(&Alds[w][c * 132 + ks * 16 + 4 * g]);
        #pragma unroll
        for (int t = 0; t < 8; ++t) {
            h4_t bf = *(const h4_t*)(&Blds[((ks * 8 + t) * 64 + l) * 4]);
            acc[t] = __builtin_amdgcn_mfma_f32_16x16x16f16(af, bf, acc[t], 0, 0, 0);
        }
    }

    #pragma unroll
    for (int t = 0; t < 8; ++t) {
        #pragma unroll
        for (int r = 0; r < 4; ++r) {
            int v = v0 + 4 * g + r;
            if (v < n) ft[(size_t)v * FDIM + t * 16 + c] = __float2half(acc[t][r]);
        }
    }
    float al0[4], al1v[4], ar0[4], ar1v[4];
    #pragma unroll
    for (int h = 0; h < 4; ++h) {
        al0[h] = al[h * 32 + c]; al1v[h] = al[h * 32 + 16 + c];
        ar0[h] = ar[h * 32 + c]; ar1v[h] = ar[h * 32 + 16 + c];
    }
    #pragma unroll
    for (int r = 0; r < 4; ++r) {
        int v = v0 + 4 * g + r;
        #pragma unroll
        for (int h = 0; h < 4; ++h) {
            float p1 = acc[2 * h][r] * al0[h] + acc[2 * h + 1][r] * al1v[h];
            float p2 = acc[2 * h][r] * ar0[h] + acc[2 * h + 1][r] * ar1v[h];
            #pragma unroll
            for (int off = 1; off < 16; off <<= 1) {
                p1 += __shfl_xor(p1, off);
                p2 += __shfl_xor(p2, off);
            }
            if (c == h && v < n) {
                a1[v * 4 + h] = p1;
                a2[v * 4 + h] = p2;
            }
        }
    }
}

// ---------------- aggregate #2: wave-per-node, no-max softmax, post-divide ----------------
__global__ void k_agg2(const int* __restrict__ offs, const int* __restrict__ csr,
                       const __half* __restrict__ ft, const float* __restrict__ a1,
                       const float* __restrict__ a2, __half* __restrict__ out, int n) {
    __shared__ float wlds[4][64 * 4];
    int tid = threadIdx.x, lane = tid & 63, w = tid >> 6;
    int v = blockIdx.x * 4 + w;
    if (v >= n) return;
    int beg = offs[v], end = offs[v + 1];
    int deg = end - beg;
    float4 a2v = *(const float4*)(a2 + v * 4);
    int h = lane >> 4;
    int f = 2 * lane;
    float2 acc = make_float2(0.f, 0.f);
    float4 dsum = make_float4(0.f, 0.f, 0.f, 0.f);
    float* wbuf = wlds[w];
    for (int base = 0; base < deg; base += 64) {
        int m = min(64, deg - base);
        int u = 0;
        float4 wgt = make_float4(0.f, 0.f, 0.f, 0.f);
        if (lane < m) {
            u = csr[beg + base + lane];
            float4 a1u = *(const float4*)(a1 + u * 4);
            wgt.x = __expf(lrelu(a1u.x + a2v.x));
            wgt.y = __expf(lrelu(a1u.y + a2v.y));
            wgt.z = __expf(lrelu(a1u.z + a2v.z));
            wgt.w = __expf(lrelu(a1u.w + a2v.w));
        }
        dsum.x += wgt.x; dsum.y += wgt.y; dsum.z += wgt.z; dsum.w += wgt.w;
        *(float4*)(wbuf + lane * 4) = wgt;
        int j = 0;
        for (; j + 4 <= m; j += 4) {
            int s0 = __builtin_amdgcn_readlane(u, j);
            int s1 = __builtin_amdgcn_readlane(u, j + 1);
            int s2 = __builtin_amdgcn_readlane(u, j + 2);
            int s3 = __builtin_amdgcn_readlane(u, j + 3);
            float w0 = wbuf[(j + 0) * 4 + h];
            float w1 = wbuf[(j + 1) * 4 + h];
            float w2 = wbuf[(j + 2) * 4 + h];
            float w3 = wbuf[(j + 3) * 4 + h];
            float2 g0 = __half22float2(*(const __half2*)(ft + (size_t)s0 * FDIM + f));
            float2 g1 = __half22float2(*(const __half2*)(ft + (size_t)s1 * FDIM + f));
            float2 g2 = __half22float2(*(const __half2*)(ft + (size_t)s2 * FDIM + f));
            float2 g3 = __half22float2(*(const __half2*)(ft + (size_t)s3 * FDIM + f));
            acc.x = fmaf(w0, g0.x, acc.x); acc.y = fmaf(w0, g0.y, acc.y);
            acc.x = fmaf(w1, g1.x, acc.x); acc.y = fmaf(w1, g1.y, acc.y);
            acc.x = fmaf(w2, g2.x, acc.x); acc.y = fmaf(w2, g2.y, acc.y);
            acc.x = fmaf(w3, g3.x, acc.x); acc.y = fmaf(w3, g3.y, acc.y);
        }
        for (; j < m; ++j) {
            int s0 = __builtin_amdgcn_readlane(u, j);
            float w0 = wbuf[j * 4 + h];
            float2 g0 = __half22float2(*(const __half2*)(ft + (size_t)s0 * FDIM + f));
            acc.x = fmaf(w0, g0.x, acc.x); acc.y = fmaf(w0, g0.y, acc.y);
        }
    }
    #pragma unroll
    for (int off = 1; off < 64; off <<= 1) {
        dsum.x += __shfl_xor(dsum.x, off);
        dsum.y += __shfl_xor(dsum.y, off);
        dsum.z += __shfl_xor(dsum.z, off);
        dsum.w += __shfl_xor(dsum.w, off);
    }
    float dh = (h < 2) ? (h == 0 ? dsum.x : dsum.y) : (h == 2 ? dsum.z : dsum.w);
    float r = 1.0f / dh;
    *(__half2*)(out + (size_t)v * FDIM + f) =
        __floats2half2_rn(fmaxf(acc.x * r, 0.f), fmaxf(acc.y * r, 0.f));
}

// ---------------- per-graph mean pooling (run-length + atomics) ----------------
__global__ void k_pool(const __half* __restrict__ hbuf, const int* __restrict__ gid,
                       float* __restrict__ gsum, int* __restrict__ gcnt, int n) {
    const int STRIP = 32;
    int wv = (blockIdx.x * blockDim.x + threadIdx.x) >> 6;
    int lane = threadIdx.x & 63;
    int beg = wv * STRIP;
    if (beg >= n) return;
    int end = min(beg + STRIP, n);
    int f = 2 * lane;
    float2 acc = make_float2(0.f, 0.f);
    int cur = gid[beg];
    int cnt = 0;
    for (int i = beg; i < end; ++i) {
        int g = gid[i];
        if (g != cur) {
            atomicAdd(&gsum[cur * FDIM + f], acc.x);
            atomicAdd(&gsum[cur * FDIM + f + 1], acc.y);
            if (lane == 0) atomicAdd(&gcnt[cur], cnt);
            acc = make_float2(0.f, 0.f); cnt = 0; cur = g;
        }
        float2 x = __half22float2(*(const __half2*)(hbuf + (size_t)i * FDIM + f));
        acc.x += x.x; acc.y += x.y; cnt++;
    }
    atomicAdd(&gsum[cur * FDIM + f], acc.x);
    atomicAdd(&gsum[cur * FDIM + f + 1], acc.y);
    if (lane == 0) atomicAdd(&gcnt[cur], cnt);
}

// ---------------- classifier ----------------
__global__ void k_classify(const float* __restrict__ gsum, const int* __restrict__ gcnt,
                           const float* __restrict__ Wc, const float* __restrict__ bc,
                           float* __restrict__ out) {
    int idx = blockIdx.x * blockDim.x + threadIdx.x;
    if (idx >= NGRAPH * NCLASS) return;
    int g = idx / NCLASS, c = idx % NCLASS;
    float rc = 1.0f / fmaxf((float)gcnt[g], 1.0f);
    float s = bc[c];
    for (int k = 0; k < FDIM; ++k)
        s += gsum[g * FDIM + k] * rc * Wc[k * NCLASS + c];
    out[idx] = 1.0f / (1.0f + __expf(-s));
}

extern "C" void kernel_launch(void* const* d_in, const int* in_sizes, int n_in,
                              void* d_out, int out_size, void* d_ws, size_t ws_size,
                              hipStream_t stream) {
    const int*   src = (const int*)d_in[0];
    const int*   dst = (const int*)d_in[1];
    const int*   gid = (const int*)d_in[2];
    const float* W1  = (const float*)d_in[3];
    const float* al1 = (const float*)d_in[4];
    const float* ar1 = (const float*)d_in[5];
    const float* W2  = (const float*)d_in[6];
    const float* al2 = (const float*)d_in[7];
    const float* ar2 = (const float*)d_in[8];
    const float* Wc  = (const float*)d_in[9];
    const float* bc  = (const float*)d_in[10];
    float* out = (float*)d_out;
    const int E = in_sizes[0];
    const int N = in_sizes[2];

    char* ws = (char*)d_ws;
    size_t off = 0;
    auto alloc = [&](size_t bytes) -> void* {
        void* p = ws + off;
        off = (off + bytes + 255) & ~(size_t)255;
        return p;
    };
    int*    deg    = (int*)alloc((size_t)N * 4);
    int*    offs   = (int*)alloc((size_t)(N + 1) * 4);
    int*    csr    = (int*)alloc((size_t)E * 4);
    int2*   part   = (int2*)alloc((size_t)E * 8);
    int*    bcnt   = (int*)alloc(NBP * 4);
    int*    bbase  = (int*)alloc(NBP * 4);
    int*    bcur   = (int*)alloc(NBP * 4);
    int*    bsum   = (int*)alloc((size_t)((N + 1023) / 1024) * 4);
    float*  h4t    = (float*)alloc((size_t)N * 4 * 4);
    float*  a1     = (float*)alloc((size_t)N * HEADS * 4);
    float*  a2     = (float*)alloc((size_t)N * HEADS * 4);
    float*  Sbuf   = (float*)alloc((size_t)N * 16 * 4);
    __half* ft16   = (__half*)alloc((size_t)N * FDIM * 2);
    __half* hbuf   = (__half*)alloc((size_t)N * FDIM * 2);
    __half* Wfrag  = (__half*)alloc((size_t)FDIM * FDIM * 2);
    float*  gsum   = (float*)alloc((size_t)NGRAPH * FDIM * 4);
    int*    gcnt   = (int*)alloc((size_t)NGRAPH * 4);

    int pb_edges = (E + SLICE - 1) / SLICE;      // partition blocks
    int nb2 = (N + NBW - 1) / NBW;               // buckets actually used
    int nb = (N + 1023) / 1024;

    k_zb<<<1, 256, 0, stream>>>(bcnt);
    k_bhist<<<pb_edges, 256, 0, stream>>>(dst, E, bcnt);
    k_bscan2<<<1, 256, 0, stream>>>(bcnt, bbase, bcur);
    k_part<<<pb_edges, 256, 0, stream>>>(src, dst, E, bcur, part);
    k_deg<<<nb2, 256, 0, stream>>>(part, bbase, bcnt, deg, N);
    k_bsum<<<nb, 256, 0, stream>>>(deg, bsum, N);
    k_bscan<<<1, 64, 0, stream>>>(bsum, nb, offs, N, E);
    k_offs<<<nb, 256, 0, stream>>>(deg, bsum, offs, gsum, gcnt, N);
    k_scatter2<<<nb2, 256, 0, stream>>>(part, bbase, bcnt, offs, csr, N);

    k_atts1<<<(N + 255) / 256, 256, 0, stream>>>(deg, W1, al1, ar1, h4t, a1, a2, N);
    k_agg1<<<(N + 15) / 16, 256, 0, stream>>>(offs, csr, h4t, a1, a2, Sbuf, N);
    k_wfrag<<<16, 256, 0, stream>>>(W2, Wfrag);
    k_layer2<<<(N + 63) / 64, 256, 0, stream>>>(Sbuf, W1, Wfrag, al2, ar2, ft16, a1, a2, N);
    k_agg2<<<(N + 3) / 4, 256, 0, stream>>>(offs, csr, ft16, a1, a2, hbuf, N);

    int pb = (((N + 31) / 32) + 3) / 4;
    k_pool<<<pb, 256, 0, stream>>>(hbuf, gid, gsum, gcnt, N);
    k_classify<<<(NGRAPH * NCLASS + 255) / 256, 256, 0, stream>>>(gsum, gcnt, Wc, bc, out);
}

// Round 8
// 141.988 us; speedup vs baseline: 2.9500x; 1.0926x over previous
//
#include <hip/hip_runtime.h>
#include <hip/hip_fp16.h>
#include <math.h>

#define HEADS 4
#define HDIM 32
#define FDIM 128   // HEADS*HDIM
#define NGRAPH 128
#define NCLASS 10

#define NBW 128            // nodes per bucket (bucket = dst >> 7)
#define NBP 512            // padded bucket count (>= ceil(50000/128)=391)
#define SLICE 4096         // edges per partition block

typedef _Float16 h4_t __attribute__((ext_vector_type(4)));
typedef float f4_t __attribute__((ext_vector_type(4)));
typedef float f2_t __attribute__((ext_vector_type(2)));

__device__ __forceinline__ float lrelu(float x) { return fmaxf(x, 0.2f * x); }

// ---------------- zero small bucket arrays ----------------
__global__ void k_zb(int* __restrict__ bcnt) {
    int i = threadIdx.x;
    bcnt[i] = 0; bcnt[i + 256] = 0;
}

// ---------------- bucket histogram (LDS-staged, few global atomics) ----------------
__global__ void k_bhist(const int* __restrict__ dst, int E, int* __restrict__ bcnt) {
    __shared__ int lcnt[NBP];
    int tid = threadIdx.x;
    for (int i = tid; i < NBP; i += 256) lcnt[i] = 0;
    __syncthreads();
    int beg = blockIdx.x * SLICE, end = min(E, beg + SLICE);
    for (int i = beg + tid; i < end; i += 256)
        atomicAdd(&lcnt[dst[i] >> 7], 1);
    __syncthreads();
    for (int i = tid; i < NBP; i += 256)
        if (lcnt[i]) atomicAdd(&bcnt[i], lcnt[i]);
}

// ---------------- exclusive scan of 512 bucket counts (1 block) ----------------
__global__ void k_bscan2(const int* __restrict__ bcnt, int* __restrict__ bbase,
                         int* __restrict__ bcur) {
    __shared__ int ws[4];
    int tid = threadIdx.x, lane = tid & 63, w = tid >> 6;
    int c0 = bcnt[2 * tid], c1 = bcnt[2 * tid + 1];
    int t = c0 + c1;
    int incl = t;
    #pragma unroll
    for (int off = 1; off < 64; off <<= 1) {
        int y = __shfl_up(incl, off);
        if (lane >= off) incl += y;
    }
    if (lane == 63) ws[w] = incl;
    __syncthreads();
    int wpre = 0;
    #pragma unroll
    for (int j = 0; j < 4; ++j) if (j < w) wpre += ws[j];
    int ex = wpre + (incl - t);
    bbase[2 * tid] = ex;          bcur[2 * tid] = ex;
    bbase[2 * tid + 1] = ex + c0; bcur[2 * tid + 1] = ex + c0;
}

// ---------------- partition edges into bucket-grouped part[] (coalesced writes) ----------------
__global__ __launch_bounds__(256) void k_part(const int* __restrict__ src,
        const int* __restrict__ dst, int E, int* __restrict__ bcur,
        int2* __restrict__ part) {
    __shared__ int lcnt[NBP];
    __shared__ int loff[NBP];
    __shared__ int lpos[NBP];
    __shared__ int2 staged[SLICE];
    __shared__ int tgt[SLICE];
    __shared__ int ws[4];
    int tid = threadIdx.x, lane = tid & 63, w = tid >> 6;
    int beg = blockIdx.x * SLICE, end = min(E, beg + SLICE);
    int m = end - beg;
    for (int i = tid; i < NBP; i += 256) lcnt[i] = 0;
    __syncthreads();
    for (int i = beg + tid; i < end; i += 256)
        atomicAdd(&lcnt[dst[i] >> 7], 1);
    __syncthreads();
    int c0 = lcnt[2 * tid], c1 = lcnt[2 * tid + 1];
    int t = c0 + c1;
    int incl = t;
    #pragma unroll
    for (int off = 1; off < 64; off <<= 1) {
        int y = __shfl_up(incl, off);
        if (lane >= off) incl += y;
    }
    if (lane == 63) ws[w] = incl;
    __syncthreads();
    int wpre = 0;
    #pragma unroll
    for (int j = 0; j < 4; ++j) if (j < w) wpre += ws[j];
    int ex = wpre + (incl - t);
    loff[2 * tid] = ex; loff[2 * tid + 1] = ex + c0;
    if (c0) lpos[2 * tid] = atomicAdd(&bcur[2 * tid], c0);
    if (c1) lpos[2 * tid + 1] = atomicAdd(&bcur[2 * tid + 1], c1);
    lcnt[2 * tid] = 0; lcnt[2 * tid + 1] = 0;
    __syncthreads();
    for (int i = beg + tid; i < end; i += 256) {
        int s = src[i], d = dst[i];
        int b = d >> 7;
        int idx = atomicAdd(&lcnt[b], 1);
        int slot = loff[b] + idx;
        staged[slot] = make_int2(s, d);
        tgt[slot] = lpos[b] + idx;
    }
    __syncthreads();
    for (int i = tid; i < m; i += 256)
        part[tgt[i]] = staged[i];
}

// ---------------- fused deg + offs + CSR scatter (one block per bucket) ----------------
__global__ __launch_bounds__(256) void k_build(const int2* __restrict__ part,
        const int* __restrict__ bbase, const int* __restrict__ bcnt,
        int* __restrict__ deg, int* __restrict__ offs, int* __restrict__ csr,
        int n, int E) {
    __shared__ int ldeg[NBW];
    __shared__ int loffs[NBW];
    __shared__ int wtot[2];
    int b = blockIdx.x, tid = threadIdx.x;
    int lane = tid & 63, w = tid >> 6;
    if (tid < NBW) ldeg[tid] = 0;
    __syncthreads();
    int beg = bbase[b], end = beg + bcnt[b];
    for (int i = beg + tid; i < end; i += 256)
        atomicAdd(&ldeg[part[i].y & (NBW - 1)], 1);
    __syncthreads();
    // exclusive scan of ldeg[128] (2 waves participate)
    int x = (tid < NBW) ? ldeg[tid] : 0;
    int incl = x;
    #pragma unroll
    for (int off = 1; off < 64; off <<= 1) {
        int y = __shfl_up(incl, off);
        if (lane >= off) incl += y;
    }
    if (tid < NBW && lane == 63) wtot[w] = incl;
    __syncthreads();
    if (tid < NBW) {
        int pre = incl - x;
        if (w == 1) pre += wtot[0];
        loffs[tid] = beg + pre;
        int v = b * NBW + tid;
        if (v < n) { deg[v] = x; offs[v] = beg + pre; }
    }
    if (b == 0 && tid == 0) offs[n] = E;
    __syncthreads();
    if (tid < NBW) ldeg[tid] = 0;   // reuse as cursor
    __syncthreads();
    for (int i = beg + tid; i < end; i += 256) {
        int2 e = part[i];
        int lv = e.y & (NBW - 1);
        int p = atomicAdd(&ldeg[lv], 1);
        csr[loffs[lv] + p] = e.x;
    }
}

// ---------------- layer-1 node features + attention coefficients ----------------
__global__ void k_atts1(const int* __restrict__ deg, const float* __restrict__ W1,
                        const float* __restrict__ al, const float* __restrict__ ar,
                        float* __restrict__ h4t, float* __restrict__ a1,
                        float* __restrict__ a2, int n) {
    __shared__ float wla[16], wlr[16];   // [k*4 + h]
    int tid = threadIdx.x;
    if (tid < 32) {
        int k = (tid & 15) >> 2, h = tid & 3;
        const float* av = (tid < 16) ? al : ar;
        float s = 0.f;
        #pragma unroll
        for (int d = 0; d < 32; ++d) s += W1[k * FDIM + h * HDIM + d] * av[h * HDIM + d];
        if (tid < 16) wla[k * 4 + h] = s; else wlr[k * 4 + h] = s;
    }
    __syncthreads();
    int v = blockIdx.x * blockDim.x + tid;
    if (v >= n) return;
    float d = (float)deg[v];
    float4 hv = make_float4(d, (d - 3.0f > 0.0f) ? 1.0f : 0.0f, 3.0f / d,
                            (d - 4.0f > 0.0f) ? 1.0f : 0.0f);
    *(float4*)(h4t + v * 4) = hv;
    float4 o1, o2;
    #pragma unroll
    for (int h = 0; h < 4; ++h) {
        float s1 = hv.x * wla[0 + h] + hv.y * wla[4 + h] + hv.z * wla[8 + h] + hv.w * wla[12 + h];
        float s2 = hv.x * wlr[0 + h] + hv.y * wlr[4 + h] + hv.z * wlr[8 + h] + hv.w * wlr[12 + h];
        if (h == 0) { o1.x = s1; o2.x = s2; } else if (h == 1) { o1.y = s1; o2.y = s2; }
        else if (h == 2) { o1.z = s1; o2.z = s2; } else { o1.w = s1; o2.w = s2; }
    }
    *(float4*)(a1 + v * 4) = o1;
    *(float4*)(a2 + v * 4) = o2;
}

// ---------------- aggregate #1 in 4-dim feature space ----------------
__global__ void k_agg1(const int* __restrict__ offs, const int* __restrict__ csr,
                       const float* __restrict__ h4t, const float* __restrict__ a1,
                       const float* __restrict__ a2, float* __restrict__ S, int n) {
    int tid = threadIdx.x, lane = tid & 63, w = tid >> 6;
    int g = lane >> 4, e = lane & 15;
    int v = (blockIdx.x * 4 + w) * 4 + g;
    bool vok = v < n;
    int beg = 0, end = 0;
    if (vok) { beg = offs[v]; end = offs[v + 1]; }
    int deg = end - beg;
    float4 a2v = vok ? *(const float4*)(a2 + v * 4) : make_float4(0, 0, 0, 0);
    float P[4][4]; float D[4];
    #pragma unroll
    for (int h = 0; h < 4; ++h) { D[h] = 0.f;
        #pragma unroll
        for (int d = 0; d < 4; ++d) P[h][d] = 0.f; }
    for (int base = 0; base < deg; base += 16) {
        if (base + e < deg) {
            int u = csr[beg + base + e];
            float4 a1u = *(const float4*)(a1 + u * 4);
            float4 f4  = *(const float4*)(h4t + u * 4);
            float wgt[4];
            wgt[0] = __expf(lrelu(a1u.x + a2v.x));
            wgt[1] = __expf(lrelu(a1u.y + a2v.y));
            wgt[2] = __expf(lrelu(a1u.z + a2v.z));
            wgt[3] = __expf(lrelu(a1u.w + a2v.w));
            #pragma unroll
            for (int h = 0; h < 4; ++h) {
                D[h] += wgt[h];
                P[h][0] = fmaf(wgt[h], f4.x, P[h][0]);
                P[h][1] = fmaf(wgt[h], f4.y, P[h][1]);
                P[h][2] = fmaf(wgt[h], f4.z, P[h][2]);
                P[h][3] = fmaf(wgt[h], f4.w, P[h][3]);
            }
        }
    }
    #pragma unroll
    for (int off = 1; off < 16; off <<= 1) {
        #pragma unroll
        for (int h = 0; h < 4; ++h) {
            D[h] += __shfl_xor(D[h], off);
            #pragma unroll
            for (int d = 0; d < 4; ++d) P[h][d] += __shfl_xor(P[h][d], off);
        }
    }
    if (vok && e == 0) {
        #pragma unroll
        for (int h = 0; h < 4; ++h) {
            float r = 1.0f / D[h];
            *(float4*)(S + v * 16 + h * 4) =
                make_float4(P[h][0] * r, P[h][1] * r, P[h][2] * r, P[h][3] * r);
        }
    }
}

// ---------------- W2 -> fp16 fragments in MFMA lane order (+ zero gsum/gcnt) ----------------
__global__ void k_wfrag(const float* __restrict__ W2, __half* __restrict__ Wfrag,
                        float* __restrict__ gsum, int* __restrict__ gcnt) {
    int gid = blockIdx.x * 256 + threadIdx.x;   // 4096 threads
    ((float4*)gsum)[gid] = make_float4(0.f, 0.f, 0.f, 0.f);   // 4096 float4 = NGRAPH*FDIM
    if (gid < NGRAPH) gcnt[gid] = 0;
    int fid = gid >> 6, l = gid & 63;
    int ks = fid >> 3, t = fid & 7;
    int k0 = ks * 16 + 4 * (l >> 4);
    int n0 = t * 16 + (l & 15);
    __half2 lo = __floats2half2_rn(W2[(k0 + 0) * FDIM + n0], W2[(k0 + 1) * FDIM + n0]);
    __half2 hi = __floats2half2_rn(W2[(k0 + 2) * FDIM + n0], W2[(k0 + 3) * FDIM + n0]);
    size_t base = ((size_t)fid * 64 + l) * 4;
    *(__half2*)(Wfrag + base)     = lo;
    *(__half2*)(Wfrag + base + 2) = hi;
}

// ---------------- layer 2 via MFMA: ft(fp8) = relu(S@W1) @ W2, + attn coeffs ----------------
__global__ __launch_bounds__(256) void k_layer2(const float* __restrict__ S,
        const float* __restrict__ W1, const __half* __restrict__ Wfrag,
        const float* __restrict__ al, const float* __restrict__ ar,
        unsigned char* __restrict__ ft8, float* __restrict__ a1,
        float* __restrict__ a2, int n) {
    __shared__ __half Blds[64 * 64 * 4];        // 32 KB
    __shared__ __half Alds[4][16 * 132];
    int tid = threadIdx.x, l = tid & 63, w = tid >> 6;
    int c = l & 15, g = l >> 4;

    #pragma unroll
    for (int i = 0; i < 8; ++i)
        ((float4*)Blds)[i * 256 + tid] = ((const float4*)Wfrag)[i * 256 + tid];

    int v0 = (blockIdx.x * 4 + w) * 16;
    float2 w1c[4];
    #pragma unroll
    for (int d = 0; d < 4; ++d) w1c[d] = *(const float2*)(W1 + d * FDIM + 2 * l);
    for (int jj = 0; jj < 16; ++jj) {
        int v = min(v0 + jj, n - 1);
        float4 s = *(const float4*)(S + v * 16 + g * 4);
        float t0 = s.x * w1c[0].x + s.y * w1c[1].x + s.z * w1c[2].x + s.w * w1c[3].x;
        float t1 = s.x * w1c[0].y + s.y * w1c[1].y + s.z * w1c[2].y + s.w * w1c[3].y;
        *(__half2*)(&Alds[w][jj * 132 + 2 * l]) = __floats2half2_rn(fmaxf(t0, 0.f), fmaxf(t1, 0.f));
    }
    __syncthreads();

    f4_t acc[8];
    #pragma unroll
    for (int t = 0; t < 8; ++t) acc[t] = (f4_t){0.f, 0.f, 0.f, 0.f};
    #pragma unroll
    for (int ks = 0; ks < 8; ++ks) {
        h4_t af = *(const h4_t*)(&Alds[w][c * 132 + ks * 16 + 4 * g]);
        #pragma unroll
        for (int t = 0; t < 8; ++t) {
            h4_t bf = *(const h4_t*)(&Blds[((ks * 8 + t) * 64 + l) * 4]);
            acc[t] = __builtin_amdgcn_mfma_f32_16x16x16f16(af, bf, acc[t], 0, 0, 0);
        }
    }

    // ft stores as fp8 e4m3 (hardware convert; round-trips with agg2's decode)
    #pragma unroll
    for (int t = 0; t < 8; ++t) {
        #pragma unroll
        for (int r = 0; r < 4; ++r) {
            int v = v0 + 4 * g + r;
            if (v < n) {
                int pk = __builtin_amdgcn_cvt_pk_fp8_f32(acc[t][r], acc[t][r], 0, false);
                ft8[(size_t)v * FDIM + t * 16 + c] = (unsigned char)(pk & 0xff);
            }
        }
    }
    float al0[4], al1v[4], ar0[4], ar1v[4];
    #pragma unroll
    for (int h = 0; h < 4; ++h) {
        al0[h] = al[h * 32 + c]; al1v[h] = al[h * 32 + 16 + c];
        ar0[h] = ar[h * 32 + c]; ar1v[h] = ar[h * 32 + 16 + c];
    }
    #pragma unroll
    for (int r = 0; r < 4; ++r) {
        int v = v0 + 4 * g + r;
        #pragma unroll
        for (int h = 0; h < 4; ++h) {
            float p1 = acc[2 * h][r] * al0[h] + acc[2 * h + 1][r] * al1v[h];
            float p2 = acc[2 * h][r] * ar0[h] + acc[2 * h + 1][r] * ar1v[h];
            #pragma unroll
            for (int off = 1; off < 16; off <<= 1) {
                p1 += __shfl_xor(p1, off);
                p2 += __shfl_xor(p2, off);
            }
            if (c == h && v < n) {
                a1[v * 4 + h] = p1;
                a2[v * 4 + h] = p2;
            }
        }
    }
}

// ---------------- aggregate #2: wave-per-node, fp8 gather, post-divide ----------------
__global__ void k_agg2(const int* __restrict__ offs, const int* __restrict__ csr,
                       const unsigned char* __restrict__ ft8, const float* __restrict__ a1,
                       const float* __restrict__ a2, __half* __restrict__ out, int n) {
    __shared__ float wlds[4][64 * 4];
    int tid = threadIdx.x, lane = tid & 63, w = tid >> 6;
    int v = blockIdx.x * 4 + w;
    if (v >= n) return;
    int beg = offs[v], end = offs[v + 1];
    int deg = end - beg;
    float4 a2v = *(const float4*)(a2 + v * 4);
    int h = lane >> 4;
    int f = 2 * lane;
    float2 acc = make_float2(0.f, 0.f);
    float4 dsum = make_float4(0.f, 0.f, 0.f, 0.f);
    float* wbuf = wlds[w];
    for (int base = 0; base < deg; base += 64) {
        int m = min(64, deg - base);
        int u = 0;
        float4 wgt = make_float4(0.f, 0.f, 0.f, 0.f);
        if (lane < m) {
            u = csr[beg + base + lane];
            float4 a1u = *(const float4*)(a1 + u * 4);
            wgt.x = __expf(lrelu(a1u.x + a2v.x));
            wgt.y = __expf(lrelu(a1u.y + a2v.y));
            wgt.z = __expf(lrelu(a1u.z + a2v.z));
            wgt.w = __expf(lrelu(a1u.w + a2v.w));
        }
        dsum.x += wgt.x; dsum.y += wgt.y; dsum.z += wgt.z; dsum.w += wgt.w;
        *(float4*)(wbuf + lane * 4) = wgt;
        int j = 0;
        for (; j + 4 <= m; j += 4) {
            int s0 = __builtin_amdgcn_readlane(u, j);
            int s1 = __builtin_amdgcn_readlane(u, j + 1);
            int s2 = __builtin_amdgcn_readlane(u, j + 2);
            int s3 = __builtin_amdgcn_readlane(u, j + 3);
            float w0 = wbuf[(j + 0) * 4 + h];
            float w1 = wbuf[(j + 1) * 4 + h];
            float w2 = wbuf[(j + 2) * 4 + h];
            float w3 = wbuf[(j + 3) * 4 + h];
            int b0 = *(const unsigned short*)(ft8 + (size_t)s0 * FDIM + f);
            int b1 = *(const unsigned short*)(ft8 + (size_t)s1 * FDIM + f);
            int b2 = *(const unsigned short*)(ft8 + (size_t)s2 * FDIM + f);
            int b3 = *(const unsigned short*)(ft8 + (size_t)s3 * FDIM + f);
            f2_t g0 = __builtin_amdgcn_cvt_pk_f32_fp8(b0, false);
            f2_t g1 = __builtin_amdgcn_cvt_pk_f32_fp8(b1, false);
            f2_t g2 = __builtin_amdgcn_cvt_pk_f32_fp8(b2, false);
            f2_t g3 = __builtin_amdgcn_cvt_pk_f32_fp8(b3, false);
            acc.x = fmaf(w0, g0[0], acc.x); acc.y = fmaf(w0, g0[1], acc.y);
            acc.x = fmaf(w1, g1[0], acc.x); acc.y = fmaf(w1, g1[1], acc.y);
            acc.x = fmaf(w2, g2[0], acc.x); acc.y = fmaf(w2, g2[1], acc.y);
            acc.x = fmaf(w3, g3[0], acc.x); acc.y = fmaf(w3, g3[1], acc.y);
        }
        for (; j < m; ++j) {
            int s0 = __builtin_amdgcn_readlane(u, j);
            float w0 = wbuf[j * 4 + h];
            int b0 = *(const unsigned short*)(ft8 + (size_t)s0 * FDIM + f);
            f2_t g0 = __builtin_amdgcn_cvt_pk_f32_fp8(b0, false);
            acc.x = fmaf(w0, g0[0], acc.x); acc.y = fmaf(w0, g0[1], acc.y);
        }
    }
    #pragma unroll
    for (int off = 1; off < 64; off <<= 1) {
        dsum.x += __shfl_xor(dsum.x, off);
        dsum.y += __shfl_xor(dsum.y, off);
        dsum.z += __shfl_xor(dsum.z, off);
        dsum.w += __shfl_xor(dsum.w, off);
    }
    float dh = (h < 2) ? (h == 0 ? dsum.x : dsum.y) : (h == 2 ? dsum.z : dsum.w);
    float r = 1.0f / dh;
    *(__half2*)(out + (size_t)v * FDIM + f) =
        __floats2half2_rn(fmaxf(acc.x * r, 0.f), fmaxf(acc.y * r, 0.f));
}

// ---------------- per-graph mean pooling (run-length + atomics) ----------------
__global__ void k_pool(const __half* __restrict__ hbuf, const int* __restrict__ gid,
                       float* __restrict__ gsum, int* __restrict__ gcnt, int n) {
    const int STRIP = 32;
    int wv = (blockIdx.x * blockDim.x + threadIdx.x) >> 6;
    int lane = threadIdx.x & 63;
    int beg = wv * STRIP;
    if (beg >= n) return;
    int end = min(beg + STRIP, n);
    int f = 2 * lane;
    float2 acc = make_float2(0.f, 0.f);
    int cur = gid[beg];
    int cnt = 0;
    for (int i = beg; i < end; ++i) {
        int g = gid[i];
        if (g != cur) {
            atomicAdd(&gsum[cur * FDIM + f], acc.x);
            atomicAdd(&gsum[cur * FDIM + f + 1], acc.y);
            if (lane == 0) atomicAdd(&gcnt[cur], cnt);
            acc = make_float2(0.f, 0.f); cnt = 0; cur = g;
        }
        float2 x = __half22float2(*(const __half2*)(hbuf + (size_t)i * FDIM + f));
        acc.x += x.x; acc.y += x.y; cnt++;
    }
    atomicAdd(&gsum[cur * FDIM + f], acc.x);
    atomicAdd(&gsum[cur * FDIM + f + 1], acc.y);
    if (lane == 0) atomicAdd(&gcnt[cur], cnt);
}

// ---------------- classifier ----------------
__global__ void k_classify(const float* __restrict__ gsum, const int* __restrict__ gcnt,
                           const float* __restrict__ Wc, const float* __restrict__ bc,
                           float* __restrict__ out) {
    int idx = blockIdx.x * blockDim.x + threadIdx.x;
    if (idx >= NGRAPH * NCLASS) return;
    int g = idx / NCLASS, c = idx % NCLASS;
    float rc = 1.0f / fmaxf((float)gcnt[g], 1.0f);
    float s = bc[c];
    for (int k = 0; k < FDIM; ++k)
        s += gsum[g * FDIM + k] * rc * Wc[k * NCLASS + c];
    out[idx] = 1.0f / (1.0f + __expf(-s));
}

extern "C" void kernel_launch(void* const* d_in, const int* in_sizes, int n_in,
                              void* d_out, int out_size, void* d_ws, size_t ws_size,
                              hipStream_t stream) {
    const int*   src = (const int*)d_in[0];
    const int*   dst = (const int*)d_in[1];
    const int*   gid = (const int*)d_in[2];
    const float* W1  = (const float*)d_in[3];
    const float* al1 = (const float*)d_in[4];
    const float* ar1 = (const float*)d_in[5];
    const float* W2  = (const float*)d_in[6];
    const float* al2 = (const float*)d_in[7];
    const float* ar2 = (const float*)d_in[8];
    const float* Wc  = (const float*)d_in[9];
    const float* bc  = (const float*)d_in[10];
    float* out = (float*)d_out;
    const int E = in_sizes[0];
    const int N = in_sizes[2];

    char* ws = (char*)d_ws;
    size_t off = 0;
    auto alloc = [&](size_t bytes) -> void* {
        void* p = ws + off;
        off = (off + bytes + 255) & ~(size_t)255;
        return p;
    };
    int*    deg    = (int*)alloc((size_t)N * 4);
    int*    offs   = (int*)alloc((size_t)(N + 1) * 4);
    int*    csr    = (int*)alloc((size_t)E * 4);
    int2*   part   = (int2*)alloc((size_t)E * 8);
    int*    bcnt   = (int*)alloc(NBP * 4);
    int*    bbase  = (int*)alloc(NBP * 4);
    int*    bcur   = (int*)alloc(NBP * 4);
    float*  h4t    = (float*)alloc((size_t)N * 4 * 4);
    float*  a1     = (float*)alloc((size_t)N * HEADS * 4);
    float*  a2     = (float*)alloc((size_t)N * HEADS * 4);
    float*  Sbuf   = (float*)alloc((size_t)N * 16 * 4);
    unsigned char* ft8 = (unsigned char*)alloc((size_t)N * FDIM);
    __half* hbuf   = (__half*)alloc((size_t)N * FDIM * 2);
    __half* Wfrag  = (__half*)alloc((size_t)FDIM * FDIM * 2);
    float*  gsum   = (float*)alloc((size_t)NGRAPH * FDIM * 4);
    int*    gcnt   = (int*)alloc((size_t)NGRAPH * 4);

    int pb_edges = (E + SLICE - 1) / SLICE;      // partition blocks
    int nb2 = (N + NBW - 1) / NBW;               // buckets actually used

    k_zb<<<1, 256, 0, stream>>>(bcnt);
    k_bhist<<<pb_edges, 256, 0, stream>>>(dst, E, bcnt);
    k_bscan2<<<1, 256, 0, stream>>>(bcnt, bbase, bcur);
    k_part<<<pb_edges, 256, 0, stream>>>(src, dst, E, bcur, part);
    k_build<<<nb2, 256, 0, stream>>>(part, bbase, bcnt, deg, offs, csr, N, E);

    k_atts1<<<(N + 255) / 256, 256, 0, stream>>>(deg, W1, al1, ar1, h4t, a1, a2, N);
    k_agg1<<<(N + 15) / 16, 256, 0, stream>>>(offs, csr, h4t, a1, a2, Sbuf, N);
    k_wfrag<<<16, 256, 0, stream>>>(W2, Wfrag, gsum, gcnt);
    k_layer2<<<(N + 63) / 64, 256, 0, stream>>>(Sbuf, W1, Wfrag, al2, ar2, ft8, a1, a2, N);
    k_agg2<<<(N + 3) / 4, 256, 0, stream>>>(offs, csr, ft8, a1, a2, hbuf, N);

    int pb = (((N + 31) / 32) + 3) / 4;
    k_pool<<<pb, 256, 0, stream>>>(hbuf, gid, gsum, gcnt, N);
    k_classify<<<(NGRAPH * NCLASS + 255) / 256, 256, 0, stream>>>(gsum, gcnt, Wc, bc, out);
}

// Round 9
// 140.732 us; speedup vs baseline: 2.9763x; 1.0089x over previous
//
#include <hip/hip_runtime.h>
#include <hip/hip_fp16.h>
#include <math.h>

#define HEADS 4
#define HDIM 32
#define FDIM 128   // HEADS*HDIM
#define NGRAPH 128
#define NCLASS 10

#define NBW 128            // nodes per bucket (bucket = dst >> 7)
#define NBP 512            // padded bucket count (>= ceil(50000/128)=391)
#define SLICE 4096         // edges per partition block

typedef _Float16 h4_t __attribute__((ext_vector_type(4)));
typedef float f4_t __attribute__((ext_vector_type(4)));
typedef float f2_t __attribute__((ext_vector_type(2)));

__device__ __forceinline__ float lrelu(float x) { return fmaxf(x, 0.2f * x); }

// ---------------- W2 -> fp16 MFMA fragments; zero gsum/gcnt/bcnt ----------------
__global__ void k_wfrag(const float* __restrict__ W2, __half* __restrict__ Wfrag,
                        float* __restrict__ gsum, int* __restrict__ gcnt,
                        int* __restrict__ bcnt) {
    int gid = blockIdx.x * 256 + threadIdx.x;   // 4096 threads
    ((float4*)gsum)[gid] = make_float4(0.f, 0.f, 0.f, 0.f);   // NGRAPH*FDIM floats
    if (gid < NGRAPH) gcnt[gid] = 0;
    if (gid < NBP) bcnt[gid] = 0;
    int fid = gid >> 6, l = gid & 63;
    int ks = fid >> 3, t = fid & 7;
    int k0 = ks * 16 + 4 * (l >> 4);
    int n0 = t * 16 + (l & 15);
    __half2 lo = __floats2half2_rn(W2[(k0 + 0) * FDIM + n0], W2[(k0 + 1) * FDIM + n0]);
    __half2 hi = __floats2half2_rn(W2[(k0 + 2) * FDIM + n0], W2[(k0 + 3) * FDIM + n0]);
    size_t base = ((size_t)fid * 64 + l) * 4;
    *(__half2*)(Wfrag + base)     = lo;
    *(__half2*)(Wfrag + base + 2) = hi;
}

// ---------------- bucket histogram (LDS-staged) ----------------
__global__ void k_bhist(const int* __restrict__ dst, int E, int* __restrict__ bcnt) {
    __shared__ int lcnt[NBP];
    int tid = threadIdx.x;
    for (int i = tid; i < NBP; i += 256) lcnt[i] = 0;
    __syncthreads();
    int beg = blockIdx.x * SLICE, end = min(E, beg + SLICE);
    for (int i = beg + tid; i < end; i += 256)
        atomicAdd(&lcnt[dst[i] >> 7], 1);
    __syncthreads();
    for (int i = tid; i < NBP; i += 256)
        if (lcnt[i]) atomicAdd(&bcnt[i], lcnt[i]);
}

// ---------------- exclusive scan of 512 bucket counts (1 block) ----------------
__global__ void k_bscan2(const int* __restrict__ bcnt, int* __restrict__ bbase,
                         int* __restrict__ bcur) {
    __shared__ int ws[4];
    int tid = threadIdx.x, lane = tid & 63, w = tid >> 6;
    int c0 = bcnt[2 * tid], c1 = bcnt[2 * tid + 1];
    int t = c0 + c1;
    int incl = t;
    #pragma unroll
    for (int off = 1; off < 64; off <<= 1) {
        int y = __shfl_up(incl, off);
        if (lane >= off) incl += y;
    }
    if (lane == 63) ws[w] = incl;
    __syncthreads();
    int wpre = 0;
    #pragma unroll
    for (int j = 0; j < 4; ++j) if (j < w) wpre += ws[j];
    int ex = wpre + (incl - t);
    bbase[2 * tid] = ex;          bcur[2 * tid] = ex;
    bbase[2 * tid + 1] = ex + c0; bcur[2 * tid + 1] = ex + c0;
}

// ---------------- partition edges into bucket-grouped part[] (coalesced writes) ----------------
__global__ __launch_bounds__(256) void k_part(const int* __restrict__ src,
        const int* __restrict__ dst, int E, int* __restrict__ bcur,
        int2* __restrict__ part) {
    __shared__ int lcnt[NBP];
    __shared__ int loff[NBP];
    __shared__ int lpos[NBP];
    __shared__ int2 staged[SLICE];
    __shared__ int tgt[SLICE];
    __shared__ int ws[4];
    int tid = threadIdx.x, lane = tid & 63, w = tid >> 6;
    int beg = blockIdx.x * SLICE, end = min(E, beg + SLICE);
    int m = end - beg;
    for (int i = tid; i < NBP; i += 256) lcnt[i] = 0;
    __syncthreads();
    for (int i = beg + tid; i < end; i += 256)
        atomicAdd(&lcnt[dst[i] >> 7], 1);
    __syncthreads();
    int c0 = lcnt[2 * tid], c1 = lcnt[2 * tid + 1];
    int t = c0 + c1;
    int incl = t;
    #pragma unroll
    for (int off = 1; off < 64; off <<= 1) {
        int y = __shfl_up(incl, off);
        if (lane >= off) incl += y;
    }
    if (lane == 63) ws[w] = incl;
    __syncthreads();
    int wpre = 0;
    #pragma unroll
    for (int j = 0; j < 4; ++j) if (j < w) wpre += ws[j];
    int ex = wpre + (incl - t);
    loff[2 * tid] = ex; loff[2 * tid + 1] = ex + c0;
    if (c0) lpos[2 * tid] = atomicAdd(&bcur[2 * tid], c0);
    if (c1) lpos[2 * tid + 1] = atomicAdd(&bcur[2 * tid + 1], c1);
    lcnt[2 * tid] = 0; lcnt[2 * tid + 1] = 0;
    __syncthreads();
    for (int i = beg + tid; i < end; i += 256) {
        int s = src[i], d = dst[i];
        int b = d >> 7;
        int idx = atomicAdd(&lcnt[b], 1);
        int slot = loff[b] + idx;
        staged[slot] = make_int2(s, d);
        tgt[slot] = lpos[b] + idx;
    }
    __syncthreads();
    for (int i = tid; i < m; i += 256)
        part[tgt[i]] = staged[i];
}

// ---------------- fused: offs + CSR scatter + layer-1 features/attn coeffs ----------------
__global__ __launch_bounds__(256) void k_build(const int2* __restrict__ part,
        const int* __restrict__ bbase, const int* __restrict__ bcnt,
        const float* __restrict__ W1, const float* __restrict__ al,
        const float* __restrict__ ar, int* __restrict__ offs, int* __restrict__ csr,
        float* __restrict__ h4t, float* __restrict__ a1, float* __restrict__ a2,
        int n, int E) {
    __shared__ int ldeg[NBW];
    __shared__ int loffs[NBW];
    __shared__ int wtot[2];
    __shared__ float wla[16], wlr[16];   // [k*4 + h]
    int b = blockIdx.x, tid = threadIdx.x;
    int lane = tid & 63, w = tid >> 6;
    if (tid < NBW) ldeg[tid] = 0;
    if (tid < 32) {
        int k = (tid & 15) >> 2, h = tid & 3;
        const float* av = (tid < 16) ? al : ar;
        float s = 0.f;
        #pragma unroll
        for (int d = 0; d < 32; ++d) s += W1[k * FDIM + h * HDIM + d] * av[h * HDIM + d];
        if (tid < 16) wla[k * 4 + h] = s; else wlr[k * 4 + h] = s;
    }
    __syncthreads();
    int beg = bbase[b], end = beg + bcnt[b];
    for (int i = beg + tid; i < end; i += 256)
        atomicAdd(&ldeg[part[i].y & (NBW - 1)], 1);
    __syncthreads();
    // exclusive scan of ldeg[128]
    int x = (tid < NBW) ? ldeg[tid] : 0;
    int incl = x;
    #pragma unroll
    for (int off = 1; off < 64; off <<= 1) {
        int y = __shfl_up(incl, off);
        if (lane >= off) incl += y;
    }
    if (tid < NBW && lane == 63) wtot[w] = incl;
    __syncthreads();
    if (tid < NBW) {
        int pre = incl - x;
        if (w == 1) pre += wtot[0];
        loffs[tid] = beg + pre;
        int v = b * NBW + tid;
        if (v < n) {
            offs[v] = beg + pre;
            // layer-1 node features + attention coefficients
            float d = (float)x;
            float4 hv = make_float4(d, (d - 3.0f > 0.0f) ? 1.0f : 0.0f, 3.0f / d,
                                    (d - 4.0f > 0.0f) ? 1.0f : 0.0f);
            *(float4*)(h4t + v * 4) = hv;
            float4 o1, o2;
            #pragma unroll
            for (int h = 0; h < 4; ++h) {
                float s1 = hv.x * wla[0 + h] + hv.y * wla[4 + h] + hv.z * wla[8 + h] + hv.w * wla[12 + h];
                float s2 = hv.x * wlr[0 + h] + hv.y * wlr[4 + h] + hv.z * wlr[8 + h] + hv.w * wlr[12 + h];
                if (h == 0) { o1.x = s1; o2.x = s2; } else if (h == 1) { o1.y = s1; o2.y = s2; }
                else if (h == 2) { o1.z = s1; o2.z = s2; } else { o1.w = s1; o2.w = s2; }
            }
            *(float4*)(a1 + v * 4) = o1;
            *(float4*)(a2 + v * 4) = o2;
        }
    }
    if (b == 0 && tid == 0) offs[n] = E;
    __syncthreads();
    if (tid < NBW) ldeg[tid] = 0;   // reuse as cursor
    __syncthreads();
    for (int i = beg + tid; i < end; i += 256) {
        int2 e = part[i];
        int lv = e.y & (NBW - 1);
        int p = atomicAdd(&ldeg[lv], 1);
        csr[loffs[lv] + p] = e.x;
    }
}

// ---------------- fused layer 2: agg1 (gather->S) + h1 + MFMA + ft8 + attn coeffs ----------------
__global__ __launch_bounds__(256) void k_l2f(const int* __restrict__ offs,
        const int* __restrict__ csr, const float* __restrict__ h4t,
        const float* __restrict__ a1, const float* __restrict__ a2,
        const float* __restrict__ W1, const __half* __restrict__ Wfrag,
        const float* __restrict__ al, const float* __restrict__ ar,
        unsigned char* __restrict__ ft8, float* __restrict__ a1b,
        float* __restrict__ a2b, int n) {
    __shared__ __half Blds[64 * 64 * 4];        // 32 KB
    __shared__ __half Alds[4][16 * 132];
    __shared__ float Slds[4][256];              // per-wave 16 nodes x 16 S-values
    int tid = threadIdx.x, l = tid & 63, w = tid >> 6;
    int c = l & 15, g = l >> 4;

    #pragma unroll
    for (int i = 0; i < 8; ++i)
        ((float4*)Blds)[i * 256 + tid] = ((const float4*)Wfrag)[i * 256 + tid];

    int v0 = (blockIdx.x * 4 + w) * 16;

    // ---- agg1 phase: 4 rounds x 4 nodes, 16 lanes per node ----
    for (int r4 = 0; r4 < 4; ++r4) {
        int v = v0 + r4 * 4 + g;
        bool vok = v < n;
        int beg = 0, end = 0;
        if (vok) { beg = offs[v]; end = offs[v + 1]; }
        int dg = end - beg;
        float4 a2v = vok ? *(const float4*)(a2 + v * 4) : make_float4(0, 0, 0, 0);
        float P[4][4], D[4];
        #pragma unroll
        for (int h = 0; h < 4; ++h) { D[h] = 0.f;
            #pragma unroll
            for (int d = 0; d < 4; ++d) P[h][d] = 0.f; }
        for (int base2 = 0; base2 < dg; base2 += 16) {
            if (base2 + c < dg) {
                int u = csr[beg + base2 + c];
                float4 a1u = *(const float4*)(a1 + u * 4);
                float4 f4  = *(const float4*)(h4t + u * 4);
                float wgt[4];
                wgt[0] = __expf(lrelu(a1u.x + a2v.x));
                wgt[1] = __expf(lrelu(a1u.y + a2v.y));
                wgt[2] = __expf(lrelu(a1u.z + a2v.z));
                wgt[3] = __expf(lrelu(a1u.w + a2v.w));
                #pragma unroll
                for (int h = 0; h < 4; ++h) {
                    D[h] += wgt[h];
                    P[h][0] = fmaf(wgt[h], f4.x, P[h][0]);
                    P[h][1] = fmaf(wgt[h], f4.y, P[h][1]);
                    P[h][2] = fmaf(wgt[h], f4.z, P[h][2]);
                    P[h][3] = fmaf(wgt[h], f4.w, P[h][3]);
                }
            }
        }
        #pragma unroll
        for (int off = 1; off < 16; off <<= 1) {
            #pragma unroll
            for (int h = 0; h < 4; ++h) {
                D[h] += __shfl_xor(D[h], off);
                #pragma unroll
                for (int d = 0; d < 4; ++d) P[h][d] += __shfl_xor(P[h][d], off);
            }
        }
        if (vok && c == 0) {
            #pragma unroll
            for (int h = 0; h < 4; ++h) {
                float r = 1.0f / D[h];
                #pragma unroll
                for (int d = 0; d < 4; ++d)
                    Slds[w][(r4 * 4 + g) * 16 + h * 4 + d] = P[h][d] * r;
            }
        }
    }

    // ---- h1 = relu(S@W1) into A tile (reads wave-local Slds) ----
    float2 w1c[4];
    #pragma unroll
    for (int d = 0; d < 4; ++d) w1c[d] = *(const float2*)(W1 + d * FDIM + 2 * l);
    for (int jj = 0; jj < 16; ++jj) {
        float4 s = *(const float4*)(&Slds[w][jj * 16 + g * 4]);
        float t0 = s.x * w1c[0].x + s.y * w1c[1].x + s.z * w1c[2].x + s.w * w1c[3].x;
        float t1 = s.x * w1c[0].y + s.y * w1c[1].y + s.z * w1c[2].y + s.w * w1c[3].y;
        *(__half2*)(&Alds[w][jj * 132 + 2 * l]) = __floats2half2_rn(fmaxf(t0, 0.f), fmaxf(t1, 0.f));
    }
    __syncthreads();

    f4_t acc[8];
    #pragma unroll
    for (int t = 0; t < 8; ++t) acc[t] = (f4_t){0.f, 0.f, 0.f, 0.f};
    #pragma unroll
    for (int ks = 0; ks < 8; ++ks) {
        h4_t af = *(const h4_t*)(&Alds[w][c * 132 + ks * 16 + 4 * g]);
        #pragma unroll
        for (int t = 0; t < 8; ++t) {
            h4_t bf = *(const h4_t*)(&Blds[((ks * 8 + t) * 64 + l) * 4]);
            acc[t] = __builtin_amdgcn_mfma_f32_16x16x16f16(af, bf, acc[t], 0, 0, 0);
        }
    }

    // ft stores as fp8 e4m3 (hardware convert; round-trips with agg2's decode)
    #pragma unroll
    for (int t = 0; t < 8; ++t) {
        #pragma unroll
        for (int r = 0; r < 4; ++r) {
            int v = v0 + 4 * g + r;
            if (v < n) {
                int pk = __builtin_amdgcn_cvt_pk_fp8_f32(acc[t][r], acc[t][r], 0, false);
                ft8[(size_t)v * FDIM + t * 16 + c] = (unsigned char)(pk & 0xff);
            }
        }
    }
    float al0[4], al1v[4], ar0[4], ar1v[4];
    #pragma unroll
    for (int h = 0; h < 4; ++h) {
        al0[h] = al[h * 32 + c]; al1v[h] = al[h * 32 + 16 + c];
        ar0[h] = ar[h * 32 + c]; ar1v[h] = ar[h * 32 + 16 + c];
    }
    #pragma unroll
    for (int r = 0; r < 4; ++r) {
        int v = v0 + 4 * g + r;
        #pragma unroll
        for (int h = 0; h < 4; ++h) {
            float p1 = acc[2 * h][r] * al0[h] + acc[2 * h + 1][r] * al1v[h];
            float p2 = acc[2 * h][r] * ar0[h] + acc[2 * h + 1][r] * ar1v[h];
            #pragma unroll
            for (int off = 1; off < 16; off <<= 1) {
                p1 += __shfl_xor(p1, off);
                p2 += __shfl_xor(p2, off);
            }
            if (c == h && v < n) {
                a1b[v * 4 + h] = p1;
                a2b[v * 4 + h] = p2;
            }
        }
    }
}

// ---------------- aggregate #2: wave-per-node, fp8 gather, post-divide ----------------
__global__ void k_agg2(const int* __restrict__ offs, const int* __restrict__ csr,
                       const unsigned char* __restrict__ ft8, const float* __restrict__ a1,
                       const float* __restrict__ a2, __half* __restrict__ out, int n) {
    __shared__ float wlds[4][64 * 4];
    int tid = threadIdx.x, lane = tid & 63, w = tid >> 6;
    int v = blockIdx.x * 4 + w;
    if (v >= n) return;
    int beg = offs[v], end = offs[v + 1];
    int deg = end - beg;
    float4 a2v = *(const float4*)(a2 + v * 4);
    int h = lane >> 4;
    int f = 2 * lane;
    float2 acc = make_float2(0.f, 0.f);
    float4 dsum = make_float4(0.f, 0.f, 0.f, 0.f);
    float* wbuf = wlds[w];
    for (int base = 0; base < deg; base += 64) {
        int m = min(64, deg - base);
        int u = 0;
        float4 wgt = make_float4(0.f, 0.f, 0.f, 0.f);
        if (lane < m) {
            u = csr[beg + base + lane];
            float4 a1u = *(const float4*)(a1 + u * 4);
            wgt.x = __expf(lrelu(a1u.x + a2v.x));
            wgt.y = __expf(lrelu(a1u.y + a2v.y));
            wgt.z = __expf(lrelu(a1u.z + a2v.z));
            wgt.w = __expf(lrelu(a1u.w + a2v.w));
        }
        dsum.x += wgt.x; dsum.y += wgt.y; dsum.z += wgt.z; dsum.w += wgt.w;
        *(float4*)(wbuf + lane * 4) = wgt;
        int j = 0;
        for (; j + 4 <= m; j += 4) {
            int s0 = __builtin_amdgcn_readlane(u, j);
            int s1 = __builtin_amdgcn_readlane(u, j + 1);
            int s2 = __builtin_amdgcn_readlane(u, j + 2);
            int s3 = __builtin_amdgcn_readlane(u, j + 3);
            float w0 = wbuf[(j + 0) * 4 + h];
            float w1 = wbuf[(j + 1) * 4 + h];
            float w2 = wbuf[(j + 2) * 4 + h];
            float w3 = wbuf[(j + 3) * 4 + h];
            int b0 = *(const unsigned short*)(ft8 + (size_t)s0 * FDIM + f);
            int b1 = *(const unsigned short*)(ft8 + (size_t)s1 * FDIM + f);
            int b2 = *(const unsigned short*)(ft8 + (size_t)s2 * FDIM + f);
            int b3 = *(const unsigned short*)(ft8 + (size_t)s3 * FDIM + f);
            f2_t g0 = __builtin_amdgcn_cvt_pk_f32_fp8(b0, false);
            f2_t g1 = __builtin_amdgcn_cvt_pk_f32_fp8(b1, false);
            f2_t g2 = __builtin_amdgcn_cvt_pk_f32_fp8(b2, false);
            f2_t g3 = __builtin_amdgcn_cvt_pk_f32_fp8(b3, false);
            acc.x = fmaf(w0, g0[0], acc.x); acc.y = fmaf(w0, g0[1], acc.y);
            acc.x = fmaf(w1, g1[0], acc.x); acc.y = fmaf(w1, g1[1], acc.y);
            acc.x = fmaf(w2, g2[0], acc.x); acc.y = fmaf(w2, g2[1], acc.y);
            acc.x = fmaf(w3, g3[0], acc.x); acc.y = fmaf(w3, g3[1], acc.y);
        }
        for (; j < m; ++j) {
            int s0 = __builtin_amdgcn_readlane(u, j);
            float w0 = wbuf[j * 4 + h];
            int b0 = *(const unsigned short*)(ft8 + (size_t)s0 * FDIM + f);
            f2_t g0 = __builtin_amdgcn_cvt_pk_f32_fp8(b0, false);
            acc.x = fmaf(w0, g0[0], acc.x); acc.y = fmaf(w0, g0[1], acc.y);
        }
    }
    #pragma unroll
    for (int off = 1; off < 64; off <<= 1) {
        dsum.x += __shfl_xor(dsum.x, off);
        dsum.y += __shfl_xor(dsum.y, off);
        dsum.z += __shfl_xor(dsum.z, off);
        dsum.w += __shfl_xor(dsum.w, off);
    }
    float dh = (h < 2) ? (h == 0 ? dsum.x : dsum.y) : (h == 2 ? dsum.z : dsum.w);
    float r = 1.0f / dh;
    *(__half2*)(out + (size_t)v * FDIM + f) =
        __floats2half2_rn(fmaxf(acc.x * r, 0.f), fmaxf(acc.y * r, 0.f));
}

// ---------------- per-graph mean pooling (run-length + atomics) ----------------
__global__ void k_pool(const __half* __restrict__ hbuf, const int* __restrict__ gid,
                       float* __restrict__ gsum, int* __restrict__ gcnt, int n) {
    const int STRIP = 32;
    int wv = (blockIdx.x * blockDim.x + threadIdx.x) >> 6;
    int lane = threadIdx.x & 63;
    int beg = wv * STRIP;
    if (beg >= n) return;
    int end = min(beg + STRIP, n);
    int f = 2 * lane;
    float2 acc = make_float2(0.f, 0.f);
    int cur = gid[beg];
    int cnt = 0;
    for (int i = beg; i < end; ++i) {
        int g = gid[i];
        if (g != cur) {
            atomicAdd(&gsum[cur * FDIM + f], acc.x);
            atomicAdd(&gsum[cur * FDIM + f + 1], acc.y);
            if (lane == 0) atomicAdd(&gcnt[cur], cnt);
            acc = make_float2(0.f, 0.f); cnt = 0; cur = g;
        }
        float2 x = __half22float2(*(const __half2*)(hbuf + (size_t)i * FDIM + f));
        acc.x += x.x; acc.y += x.y; cnt++;
    }
    atomicAdd(&gsum[cur * FDIM + f], acc.x);
    atomicAdd(&gsum[cur * FDIM + f + 1], acc.y);
    if (lane == 0) atomicAdd(&gcnt[cur], cnt);
}

// ---------------- classifier ----------------
__global__ void k_classify(const float* __restrict__ gsum, const int* __restrict__ gcnt,
                           const float* __restrict__ Wc, const float* __restrict__ bc,
                           float* __restrict__ out) {
    int idx = blockIdx.x * blockDim.x + threadIdx.x;
    if (idx >= NGRAPH * NCLASS) return;
    int g = idx / NCLASS, c = idx % NCLASS;
    float rc = 1.0f / fmaxf((float)gcnt[g], 1.0f);
    float s = bc[c];
    for (int k = 0; k < FDIM; ++k)
        s += gsum[g * FDIM + k] * rc * Wc[k * NCLASS + c];
    out[idx] = 1.0f / (1.0f + __expf(-s));
}

extern "C" void kernel_launch(void* const* d_in, const int* in_sizes, int n_in,
                              void* d_out, int out_size, void* d_ws, size_t ws_size,
                              hipStream_t stream) {
    const int*   src = (const int*)d_in[0];
    const int*   dst = (const int*)d_in[1];
    const int*   gid = (const int*)d_in[2];
    const float* W1  = (const float*)d_in[3];
    const float* al1 = (const float*)d_in[4];
    const float* ar1 = (const float*)d_in[5];
    const float* W2  = (const float*)d_in[6];
    const float* al2 = (const float*)d_in[7];
    const float* ar2 = (const float*)d_in[8];
    const float* Wc  = (const float*)d_in[9];
    const float* bc  = (const float*)d_in[10];
    float* out = (float*)d_out;
    const int E = in_sizes[0];
    const int N = in_sizes[2];

    char* ws = (char*)d_ws;
    size_t off = 0;
    auto alloc = [&](size_t bytes) -> void* {
        void* p = ws + off;
        off = (off + bytes + 255) & ~(size_t)255;
        return p;
    };
    int*    offs   = (int*)alloc((size_t)(N + 1) * 4);
    int*    csr    = (int*)alloc((size_t)E * 4);
    int2*   part   = (int2*)alloc((size_t)E * 8);
    int*    bcnt   = (int*)alloc(NBP * 4);
    int*    bbase  = (int*)alloc(NBP * 4);
    int*    bcur   = (int*)alloc(NBP * 4);
    float*  h4t    = (float*)alloc((size_t)N * 4 * 4);
    float*  a1     = (float*)alloc((size_t)N * HEADS * 4);
    float*  a2     = (float*)alloc((size_t)N * HEADS * 4);
    float*  a1b    = (float*)alloc((size_t)N * HEADS * 4);
    float*  a2b    = (float*)alloc((size_t)N * HEADS * 4);
    unsigned char* ft8 = (unsigned char*)alloc((size_t)N * FDIM);
    __half* hbuf   = (__half*)alloc((size_t)N * FDIM * 2);
    __half* Wfrag  = (__half*)alloc((size_t)FDIM * FDIM * 2);
    float*  gsum   = (float*)alloc((size_t)NGRAPH * FDIM * 4);
    int*    gcnt   = (int*)alloc((size_t)NGRAPH * 4);

    int pb_edges = (E + SLICE - 1) / SLICE;      // partition blocks
    int nb2 = (N + NBW - 1) / NBW;               // buckets actually used

    k_wfrag<<<16, 256, 0, stream>>>(W2, Wfrag, gsum, gcnt, bcnt);
    k_bhist<<<pb_edges, 256, 0, stream>>>(dst, E, bcnt);
    k_bscan2<<<1, 256, 0, stream>>>(bcnt, bbase, bcur);
    k_part<<<pb_edges, 256, 0, stream>>>(src, dst, E, bcur, part);
    k_build<<<nb2, 256, 0, stream>>>(part, bbase, bcnt, W1, al1, ar1,
                                     offs, csr, h4t, a1, a2, N, E);
    k_l2f<<<(N + 63) / 64, 256, 0, stream>>>(offs, csr, h4t, a1, a2, W1, Wfrag,
                                             al2, ar2, ft8, a1b, a2b, N);
    k_agg2<<<(N + 3) / 4, 256, 0, stream>>>(offs, csr, ft8, a1b, a2b, hbuf, N);

    int pb = (((N + 31) / 32) + 3) / 4;
    k_pool<<<pb, 256, 0, stream>>>(hbuf, gid, gsum, gcnt, N);
    k_classify<<<(NGRAPH * NCLASS + 255) / 256, 256, 0, stream>>>(gsum, gcnt, Wc, bc, out);
}